// Round 11
// baseline (309.393 us; speedup 1.0000x reference)
//
#include <hip/hip_runtime.h>

// 2-layer GCN. zero -> part -> sort (padded CSR) -> gemm1 (channel-blocked
// bf16 hhat) -> agg1 (4 channel-block phases; per-phase gather table is
// 3.2 MB -> per-XCD L2 resident) -> gemm2 -> agg2.
// Edge-index loads wave-uniform (scalar cache) everywhere; cndmask selects
// per-lane edge; fp32 accumulation.

namespace {
constexpr int BLK = 256;
constexpr int NPB = 256;       // nodes per bucket (dstLocal fits in 8 bits)
constexpr int PCHUNK = 8192;   // edges per partition block
constexpr int STRIDE = 5120;   // padded region per bucket: mean 4096 + 16 sigma
constexpr int CPAD = 32;       // bcnt padding: 1 counter per 128 B line

__device__ inline float bf2f(unsigned short h) {
    union { unsigned u; float f; } v; v.u = (unsigned)h << 16; return v.f;
}
__device__ inline float bfl(unsigned u) {
    union { unsigned u; float f; } v; v.u = u << 16; return v.f;
}
__device__ inline float bfh(unsigned u) {
    union { unsigned u; float f; } v; v.u = u & 0xFFFF0000u; return v.f;
}
__device__ inline unsigned short f2bf(float f) {
    union { float f; unsigned u; } v; v.f = f;
    unsigned r = (v.u + 0x7FFFu + ((v.u >> 16) & 1u)) >> 16;  // RNE
    return (unsigned short)r;
}
__device__ inline unsigned pack2bf(float a, float b) {
    return (unsigned)f2bf(a) | ((unsigned)f2bf(b) << 16);
}
// select one of 4 scalar edge ids by lane slot q (0..3) — cndmask tree
__device__ inline int sel4(int s0, int s1, int s2, int s3, int q) {
    int sa = (q & 1) ? s1 : s0;
    int sb = (q & 1) ? s3 : s2;
    return (q & 2) ? sb : sa;
}

__global__ __launch_bounds__(BLK) void k_zero(int* __restrict__ p, int n) {
    int i = blockIdx.x * BLK + threadIdx.x;
    if (i < n) p[i] = 0;
}

// ---- stage 1: single-pass partition into fixed bucket regions --------------
__global__ __launch_bounds__(BLK) void k_part(const int* __restrict__ src,
                                              const int* __restrict__ dst,
                                              int* __restrict__ bcnt,
                                              unsigned* __restrict__ packed,
                                              int e, int nb) {
    __shared__ int sdst[PCHUNK];   // 32 KB
    __shared__ int hist[1024];
    __shared__ int base[1024];
    int t = threadIdx.x;
    int chunk0 = blockIdx.x * PCHUNK;
    if (chunk0 >= e) return;
    int lim = min(PCHUNK, e - chunk0);
    int lim4 = lim >> 2;
    for (int i = t; i < nb; i += BLK) hist[i] = 0;
    __syncthreads();
    const int4* d4 = (const int4*)(dst + chunk0);
    for (int i = t; i < lim4; i += BLK) {
        int4 d = d4[i];
        ((int4*)sdst)[i] = d;
        atomicAdd(&hist[d.x >> 8], 1);
        atomicAdd(&hist[d.y >> 8], 1);
        atomicAdd(&hist[d.z >> 8], 1);
        atomicAdd(&hist[d.w >> 8], 1);
    }
    for (int i = (lim4 << 2) + t; i < lim; i += BLK) {
        int d = dst[chunk0 + i];
        sdst[i] = d;
        atomicAdd(&hist[d >> 8], 1);
    }
    __syncthreads();
    for (int i = t; i < nb; i += BLK) {
        int c = hist[i];
        base[i] = c ? (i * STRIDE + atomicAdd(&bcnt[i * CPAD], c)) : 0;
        hist[i] = 0;  // reuse as within-chunk cursor
    }
    __syncthreads();
    const int4* s4 = (const int4*)(src + chunk0);
    for (int i = t; i < lim4; i += BLK) {
        int4 d = ((int4*)sdst)[i];
        int4 s = s4[i];
        int b0 = d.x >> 8, b1 = d.y >> 8, b2 = d.z >> 8, b3 = d.w >> 8;
        int r0 = atomicAdd(&hist[b0], 1);
        packed[base[b0] + r0] = ((unsigned)s.x << 8) | (unsigned)(d.x & 255);
        int r1 = atomicAdd(&hist[b1], 1);
        packed[base[b1] + r1] = ((unsigned)s.y << 8) | (unsigned)(d.y & 255);
        int r2 = atomicAdd(&hist[b2], 1);
        packed[base[b2] + r2] = ((unsigned)s.z << 8) | (unsigned)(d.z & 255);
        int r3 = atomicAdd(&hist[b3], 1);
        packed[base[b3] + r3] = ((unsigned)s.w << 8) | (unsigned)(d.w & 255);
    }
    for (int i = (lim4 << 2) + t; i < lim; i += BLK) {
        int d = sdst[i];
        int b = d >> 8;
        int r = atomicAdd(&hist[b], 1);
        packed[base[b] + r] = ((unsigned)src[chunk0 + i] << 8) | (unsigned)(d & 255);
    }
}

// ---- stage 2: per-bucket LDS-staged counting sort -> padded CSR + dinv -----
__global__ __launch_bounds__(512) void k_sort(const unsigned* __restrict__ packed,
                                              const int* __restrict__ bcnt,
                                              int* __restrict__ ssrc,
                                              int* __restrict__ rowbeg,
                                              int* __restrict__ rowcnt,
                                              float* __restrict__ dinv, int n) {
    __shared__ unsigned sp[STRIDE];   // 20 KB bucket staging
    __shared__ int cnt[NPB];
    __shared__ int offs[NPB];
    int b = blockIdx.x;
    int t = threadIdx.x;
    int regionBase = b * STRIDE;
    int ecnt = bcnt[b * CPAD];
    if (t < NPB) cnt[t] = 0;
    __syncthreads();
    for (int i = t; i < ecnt; i += 512) {
        unsigned p = packed[regionBase + i];
        sp[i] = p;
        atomicAdd(&cnt[p & 255u], 1);
    }
    __syncthreads();
    if (t < NPB) offs[t] = cnt[t];
    __syncthreads();
    for (int off = 1; off < NPB; off <<= 1) {
        int x = 0;
        if (t < NPB && t >= off) x = offs[t - off];
        __syncthreads();
        if (t < NPB) offs[t] += x;
        __syncthreads();
    }
    int myoff = 0;
    if (t < NPB) {
        int v = cnt[t];
        myoff = offs[t] - v;  // exclusive
        int node = (b << 8) + t;
        if (node < n) {
            rowbeg[node] = regionBase + myoff;
            rowcnt[node] = v;
            dinv[node] = rsqrtf((float)(v + 1));   // +1 self-loop
        }
    }
    __syncthreads();
    if (t < NPB) cnt[t] = regionBase + myoff;  // reuse as cursor
    __syncthreads();
    for (int i = t; i < ecnt; i += 512) {
        unsigned p = sp[i];
        int pos = atomicAdd(&cnt[p & 255u], 1);
        ssrc[pos] = (int)(p >> 8);
    }
}

// ---- layer kernels ---------------------------------------------------------

// hhat_b[cb][n][c16] = bf16( dinv[n] * sum_k x[n][k]*W1[k][cb*16+c16] )
// thread = 4 nodes x 16 channels (cg == cb); channel-blocked store.
__global__ __launch_bounds__(BLK) void k_gemm1(const float* __restrict__ x,
                                               const float* __restrict__ W1,
                                               const float* __restrict__ dinv,
                                               unsigned short* __restrict__ hhb, int n) {
    __shared__ float W[64 * 64];
    int t = threadIdx.x;
    #pragma unroll
    for (int i = 0; i < 16; ++i) W[t + BLK * i] = W1[t + BLK * i];
    __syncthreads();
    const int cg = t & 3;
    const int ng = t >> 2;
    const int node0 = blockIdx.x * 256 + ng * 4;
    const float* Wc = W + cg * 16;

    int nd[4];
    #pragma unroll
    for (int i = 0; i < 4; ++i) {
        int v = node0 + i;
        nd[i] = (v < n) ? v : (n - 1);
    }

    float4 acc[4][4];
    #pragma unroll
    for (int i = 0; i < 4; ++i)
        #pragma unroll
        for (int c = 0; c < 4; ++c) acc[i][c] = make_float4(0.f, 0.f, 0.f, 0.f);

    for (int k4 = 0; k4 < 16; ++k4) {
        float4 xv[4];
        #pragma unroll
        for (int i = 0; i < 4; ++i)
            xv[i] = ((const float4*)(x + (size_t)nd[i] * 64))[k4];
        #pragma unroll
        for (int kk = 0; kk < 4; ++kk) {
            const float4* wr = (const float4*)(Wc + (k4 * 4 + kk) * 64);
            float4 w0 = wr[0], w1 = wr[1], w2 = wr[2], w3 = wr[3];
            #pragma unroll
            for (int i = 0; i < 4; ++i) {
                float xa[4] = {xv[i].x, xv[i].y, xv[i].z, xv[i].w};
                float xs = xa[kk];
                acc[i][0].x = fmaf(xs, w0.x, acc[i][0].x);
                acc[i][0].y = fmaf(xs, w0.y, acc[i][0].y);
                acc[i][0].z = fmaf(xs, w0.z, acc[i][0].z);
                acc[i][0].w = fmaf(xs, w0.w, acc[i][0].w);
                acc[i][1].x = fmaf(xs, w1.x, acc[i][1].x);
                acc[i][1].y = fmaf(xs, w1.y, acc[i][1].y);
                acc[i][1].z = fmaf(xs, w1.z, acc[i][1].z);
                acc[i][1].w = fmaf(xs, w1.w, acc[i][1].w);
                acc[i][2].x = fmaf(xs, w2.x, acc[i][2].x);
                acc[i][2].y = fmaf(xs, w2.y, acc[i][2].y);
                acc[i][2].z = fmaf(xs, w2.z, acc[i][2].z);
                acc[i][2].w = fmaf(xs, w2.w, acc[i][2].w);
                acc[i][3].x = fmaf(xs, w3.x, acc[i][3].x);
                acc[i][3].y = fmaf(xs, w3.y, acc[i][3].y);
                acc[i][3].z = fmaf(xs, w3.z, acc[i][3].z);
                acc[i][3].w = fmaf(xs, w3.w, acc[i][3].w);
            }
        }
    }
    size_t cbase = (size_t)cg * ((size_t)n * 16);
    #pragma unroll
    for (int i = 0; i < 4; ++i) {
        int v = node0 + i;
        if (v < n) {
            float d = dinv[v];
            unsigned u0 = pack2bf(acc[i][0].x * d, acc[i][0].y * d);
            unsigned u1 = pack2bf(acc[i][0].z * d, acc[i][0].w * d);
            unsigned u2 = pack2bf(acc[i][1].x * d, acc[i][1].y * d);
            unsigned u3 = pack2bf(acc[i][1].z * d, acc[i][1].w * d);
            unsigned u4 = pack2bf(acc[i][2].x * d, acc[i][2].y * d);
            unsigned u5 = pack2bf(acc[i][2].z * d, acc[i][2].w * d);
            unsigned u6 = pack2bf(acc[i][3].x * d, acc[i][3].y * d);
            unsigned u7 = pack2bf(acc[i][3].z * d, acc[i][3].w * d);
            uint4* dst = (uint4*)(hhb + cbase + (size_t)v * 16);
            dst[0] = make_uint4(u0, u1, u2, u3);
            dst[1] = make_uint4(u4, u5, u6, u7);
        }
    }
}

// agg layer 1, channel-blocked: wave = (node, cb); 64 lanes = 4 edge-slots x
// 16 ch. Grid is cb-major so concurrent blocks share one 3.2 MB table
// (per-XCD L2 resident). Index loads wave-uniform; 4 gathers in flight.
__global__ __launch_bounds__(BLK) void k_agg1(const unsigned short* __restrict__ hhb,
                                              const int* __restrict__ rowbeg,
                                              const int* __restrict__ rowcnt,
                                              const int* __restrict__ ssrc,
                                              const float* __restrict__ dinv,
                                              const float* __restrict__ b1,
                                              unsigned short* __restrict__ h1b,
                                              int n, int nbn4) {
    int bid = blockIdx.x;
    int cb = bid / nbn4;
    int nblk = bid - cb * nbn4;
    int wid = __builtin_amdgcn_readfirstlane(nblk * 4 + (int)(threadIdx.x >> 6));
    int lane = threadIdx.x & 63;
    if (wid >= n) return;
    int q = lane >> 4;      // edge slot
    int c = lane & 15;      // channel within block
    size_t cbase = (size_t)cb * ((size_t)n * 16);
    const unsigned short* tab = hhb + cbase;
    int beg = rowbeg[wid];
    int cnt = rowcnt[wid];
    float a = 0.f;
    int e = 0;
    for (; e + 16 <= cnt; e += 16) {
        int s0 = ssrc[beg + e + 0],  s1 = ssrc[beg + e + 1];
        int s2 = ssrc[beg + e + 2],  s3 = ssrc[beg + e + 3];
        int s4 = ssrc[beg + e + 4],  s5 = ssrc[beg + e + 5];
        int s6 = ssrc[beg + e + 6],  s7 = ssrc[beg + e + 7];
        int s8 = ssrc[beg + e + 8],  s9 = ssrc[beg + e + 9];
        int sA = ssrc[beg + e + 10], sB = ssrc[beg + e + 11];
        int sC = ssrc[beg + e + 12], sD = ssrc[beg + e + 13];
        int sE = ssrc[beg + e + 14], sF = ssrc[beg + e + 15];
        int g0 = sel4(s0, s1, s2, s3, q);
        int g1 = sel4(s4, s5, s6, s7, q);
        int g2 = sel4(s8, s9, sA, sB, q);
        int g3 = sel4(sC, sD, sE, sF, q);
        float v0 = bf2f(tab[((size_t)g0 << 4) + c]);
        float v1 = bf2f(tab[((size_t)g1 << 4) + c]);
        float v2 = bf2f(tab[((size_t)g2 << 4) + c]);
        float v3 = bf2f(tab[((size_t)g3 << 4) + c]);
        a += (v0 + v1) + (v2 + v3);
    }
    for (; e + 4 <= cnt; e += 4) {
        int s0 = ssrc[beg + e + 0], s1 = ssrc[beg + e + 1];
        int s2 = ssrc[beg + e + 2], s3 = ssrc[beg + e + 3];
        int g = sel4(s0, s1, s2, s3, q);
        a += bf2f(tab[((size_t)g << 4) + c]);
    }
    if (e + q < cnt)  // tail 1..3 edges
        a += bf2f(tab[((size_t)ssrc[beg + e + q] << 4) + c]);
    a += __shfl_xor(a, 16, 64);
    a += __shfl_xor(a, 32, 64);
    if (q == 0) {
        float self = bf2f(tab[((size_t)wid << 4) + c]);
        float dv = dinv[wid];
        float h = fmaxf(fmaf(dv, a + self, b1[cb * 16 + c]), 0.f);
        h1b[cbase + ((size_t)wid << 4) + c] = f2bf(h);
    }
}

// h2hat[n][j] = bf16( dinv[n] * sum_c h1[n][c]*W2[c][j] ), h1 blocked bf16.
__global__ __launch_bounds__(BLK) void k_gemm2(const unsigned short* __restrict__ h1b,
                                               const float* __restrict__ W2,
                                               const float* __restrict__ dinv,
                                               unsigned short* __restrict__ h2hat, int n) {
    __shared__ float W[64 * 16];
    int t = threadIdx.x;
    #pragma unroll
    for (int i = 0; i < 4; ++i) W[t + BLK * i] = W2[t + BLK * i];
    __syncthreads();
    int node = blockIdx.x * BLK + t;
    if (node >= n) return;
    float4 a0 = make_float4(0.f, 0.f, 0.f, 0.f);
    float4 a1 = a0, a2 = a0, a3 = a0;
    #pragma unroll
    for (int cb = 0; cb < 4; ++cb) {
        const uint4* p = (const uint4*)(h1b + (size_t)cb * ((size_t)n * 16)
                                        + (size_t)node * 16);
        uint4 u0 = p[0], u1 = p[1];
        float hv[16];
        hv[0] = bfl(u0.x);  hv[1] = bfh(u0.x);
        hv[2] = bfl(u0.y);  hv[3] = bfh(u0.y);
        hv[4] = bfl(u0.z);  hv[5] = bfh(u0.z);
        hv[6] = bfl(u0.w);  hv[7] = bfh(u0.w);
        hv[8] = bfl(u1.x);  hv[9] = bfh(u1.x);
        hv[10] = bfl(u1.y); hv[11] = bfh(u1.y);
        hv[12] = bfl(u1.z); hv[13] = bfh(u1.z);
        hv[14] = bfl(u1.w); hv[15] = bfh(u1.w);
        #pragma unroll
        for (int k = 0; k < 16; ++k) {
            float h = hv[k];
            const float4* wr = (const float4*)(W + (cb * 16 + k) * 16);
            float4 w0 = wr[0], w1 = wr[1], w2 = wr[2], w3 = wr[3];
            a0.x = fmaf(h, w0.x, a0.x); a0.y = fmaf(h, w0.y, a0.y);
            a0.z = fmaf(h, w0.z, a0.z); a0.w = fmaf(h, w0.w, a0.w);
            a1.x = fmaf(h, w1.x, a1.x); a1.y = fmaf(h, w1.y, a1.y);
            a1.z = fmaf(h, w1.z, a1.z); a1.w = fmaf(h, w1.w, a1.w);
            a2.x = fmaf(h, w2.x, a2.x); a2.y = fmaf(h, w2.y, a2.y);
            a2.z = fmaf(h, w2.z, a2.z); a2.w = fmaf(h, w2.w, a2.w);
            a3.x = fmaf(h, w3.x, a3.x); a3.y = fmaf(h, w3.y, a3.y);
            a3.z = fmaf(h, w3.z, a3.z); a3.w = fmaf(h, w3.w, a3.w);
        }
    }
    float d = dinv[node];
    uint4* dst = (uint4*)(h2hat + (size_t)node * 16);
    dst[0] = make_uint4(pack2bf(a0.x * d, a0.y * d), pack2bf(a0.z * d, a0.w * d),
                        pack2bf(a1.x * d, a1.y * d), pack2bf(a1.z * d, a1.w * d));
    dst[1] = make_uint4(pack2bf(a2.x * d, a2.y * d), pack2bf(a2.z * d, a2.w * d),
                        pack2bf(a3.x * d, a3.y * d), pack2bf(a3.z * d, a3.w * d));
}

// one wave per node; 64 lanes = 4 edge-slots x 16 channels; uniform ssrc
// loads + cndmask select by slot; unroll x2 (2 gathers in flight).
__global__ __launch_bounds__(BLK) void k_agg2(const unsigned short* __restrict__ h2,
                                              const int* __restrict__ rowbeg,
                                              const int* __restrict__ rowcnt,
                                              const int* __restrict__ ssrc,
                                              const float* __restrict__ dinv,
                                              const float* __restrict__ b2,
                                              float* __restrict__ out, int n) {
    int wid = __builtin_amdgcn_readfirstlane(
        (int)((blockIdx.x * BLK + threadIdx.x) >> 6));
    int lane = threadIdx.x & 63;
    if (wid >= n) return;
    int q = lane >> 4;      // edge slot 0..3
    int c = lane & 15;      // channel
    int beg = rowbeg[wid];
    int cnt = rowcnt[wid];
    float a = 0.f;
    int e = 0;
    for (; e + 8 <= cnt; e += 8) {
        int s0 = ssrc[beg + e + 0], s1 = ssrc[beg + e + 1];
        int s2 = ssrc[beg + e + 2], s3 = ssrc[beg + e + 3];
        int s4 = ssrc[beg + e + 4], s5 = ssrc[beg + e + 5];
        int s6 = ssrc[beg + e + 6], s7 = ssrc[beg + e + 7];
        int sA = sel4(s0, s1, s2, s3, q);
        int sB = sel4(s4, s5, s6, s7, q);
        float vA = bf2f(h2[((size_t)sA << 4) + c]);
        float vB = bf2f(h2[((size_t)sB << 4) + c]);
        a += vA + vB;
    }
    if (e + 4 <= cnt) {
        int s0 = ssrc[beg + e + 0], s1 = ssrc[beg + e + 1];
        int s2 = ssrc[beg + e + 2], s3 = ssrc[beg + e + 3];
        int s = sel4(s0, s1, s2, s3, q);
        a += bf2f(h2[((size_t)s << 4) + c]);
        e += 4;
    }
    if (e + q < cnt)  // tail 1..3 edges
        a += bf2f(h2[((size_t)ssrc[beg + e + q] << 4) + c]);
    a += __shfl_xor(a, 16, 64);
    a += __shfl_xor(a, 32, 64);
    if (q == 0) {
        float self = bf2f(h2[((size_t)wid << 4) + c]);
        out[((size_t)wid << 4) + c] = fmaf(dinv[wid], a + self, b2[c]);
    }
}

} // namespace

extern "C" void kernel_launch(void* const* d_in, const int* in_sizes, int n_in,
                              void* d_out, int out_size, void* d_ws, size_t ws_size,
                              hipStream_t stream) {
    const float* x  = (const float*)d_in[0];
    const int*   ei = (const int*)d_in[1];
    const float* W1 = (const float*)d_in[2];
    const float* b1 = (const float*)d_in[3];
    const float* W2 = (const float*)d_in[4];
    const float* b2 = (const float*)d_in[5];
    float* out = (float*)d_out;

    const int N = in_sizes[0] / 64;
    const int E = in_sizes[1] / 2;
    const int* src = ei;
    const int* dst = ei + E;
    const int nb = (N + NPB - 1) / NPB;   // buckets (<=1024)

    char* ws = (char*)d_ws;
    size_t off = 0;
    auto alloc = [&](size_t bytes) -> char* {
        char* p = ws + off;
        off = (off + bytes + 255) & ~(size_t)255;
        return p;
    };
    int*            bcnt   = (int*)alloc((size_t)1024 * CPAD * 4);
    int*            rowbeg = (int*)alloc((size_t)N * 4);
    int*            rowcnt = (int*)alloc((size_t)N * 4);
    float*          dinv   = (float*)alloc((size_t)N * 4);
    unsigned*       packed = (unsigned*)alloc((size_t)nb * STRIDE * 4);
    int*            ssrc   = (int*)alloc((size_t)nb * STRIDE * 4);
    unsigned short* hhb    = (unsigned short*)alloc((size_t)N * 64 * 2);  // blocked
    unsigned short* h1b    = (unsigned short*)alloc((size_t)N * 64 * 2);  // blocked
    unsigned short* h2hat  = (unsigned short*)alloc((size_t)N * 16 * 2);

    const int nb_n = (N + BLK - 1) / BLK;
    const int nchunks = (E + PCHUNK - 1) / PCHUNK;
    const int nbn4 = (N + 3) / 4;                                    // blocks per cb
    const int nb_w = (int)(((long long)N * 64 + BLK - 1) / BLK);     // wave-per-node

    const int zn = nb * CPAD;
    k_zero<<<(zn + BLK - 1) / BLK, BLK, 0, stream>>>(bcnt, zn);
    k_part<<<nchunks, BLK, 0, stream>>>(src, dst, bcnt, packed, E, nb);
    k_sort<<<nb, 512, 0, stream>>>(packed, bcnt, ssrc, rowbeg, rowcnt, dinv, N);

    k_gemm1<<<nb_n, BLK, 0, stream>>>(x, W1, dinv, hhb, N);
    k_agg1<<<4 * nbn4, BLK, 0, stream>>>(hhb, rowbeg, rowcnt, ssrc, dinv, b1,
                                         h1b, N, nbn4);
    k_gemm2<<<nb_n, BLK, 0, stream>>>(h1b, W2, dinv, h2hat, N);
    k_agg2<<<nb_w, BLK, 0, stream>>>(h2hat, rowbeg, rowcnt, ssrc, dinv, b2, out, N);
}

// Round 12
// 216.412 us; speedup vs baseline: 1.4296x; 1.4296x over previous
//
#include <hip/hip_runtime.h>

// 2-layer GCN. zero -> part (bucket partition, padded counters, int4 loads,
// 8192-edge chunks) -> sort (LDS-staged per-bucket counting sort) -> gemm1 ->
// agg1 (QUAD-node waves, fused layer-2 GEMV) -> agg2 (dual-node waves).
// Edge-index loads kept wave-uniform (scalar cache) in both agg kernels;
// feature gathers are 64-lane ushort (bf16) with fp32 accumulation.
// Round-11 lesson: channel-blocking quadruples instruction work and does NOT
// cut the >=8x12.8MB per-XCD compulsory gather traffic — reverted.

namespace {
constexpr int BLK = 256;
constexpr int NPB = 256;       // nodes per bucket (dstLocal fits in 8 bits)
constexpr int PCHUNK = 8192;   // edges per partition block
constexpr int STRIDE = 5120;   // padded region per bucket: mean 4096 + 16 sigma
constexpr int CPAD = 32;       // bcnt padding: 1 counter per 128 B line

__device__ inline float bf2f(unsigned short h) {
    union { unsigned u; float f; } v; v.u = (unsigned)h << 16; return v.f;
}
__device__ inline unsigned short f2bf(float f) {
    union { float f; unsigned u; } v; v.f = f;
    unsigned r = (v.u + 0x7FFFu + ((v.u >> 16) & 1u)) >> 16;  // RNE
    return (unsigned short)r;
}
__device__ inline unsigned pack2bf(float a, float b) {
    return (unsigned)f2bf(a) | ((unsigned)f2bf(b) << 16);
}
// select one of 4 scalar edge ids by lane slot q (0..3) — cndmask tree
__device__ inline int sel4(int s0, int s1, int s2, int s3, int q) {
    int sa = (q & 1) ? s1 : s0;
    int sb = (q & 1) ? s3 : s2;
    return (q & 2) ? sb : sa;
}

// 8 / 4-edge gather helpers (indices wave-uniform -> scalar cache)
__device__ inline float gather8(const unsigned short* __restrict__ hhat,
                                const int* __restrict__ ssrc, int base, int lane) {
    int s0 = ssrc[base + 0], s1 = ssrc[base + 1];
    int s2 = ssrc[base + 2], s3 = ssrc[base + 3];
    int s4 = ssrc[base + 4], s5 = ssrc[base + 5];
    int s6 = ssrc[base + 6], s7 = ssrc[base + 7];
    float v0 = bf2f(hhat[((size_t)s0 << 6) + lane]);
    float v1 = bf2f(hhat[((size_t)s1 << 6) + lane]);
    float v2 = bf2f(hhat[((size_t)s2 << 6) + lane]);
    float v3 = bf2f(hhat[((size_t)s3 << 6) + lane]);
    float v4 = bf2f(hhat[((size_t)s4 << 6) + lane]);
    float v5 = bf2f(hhat[((size_t)s5 << 6) + lane]);
    float v6 = bf2f(hhat[((size_t)s6 << 6) + lane]);
    float v7 = bf2f(hhat[((size_t)s7 << 6) + lane]);
    return ((v0 + v1) + (v2 + v3)) + ((v4 + v5) + (v6 + v7));
}
__device__ inline float gather4(const unsigned short* __restrict__ hhat,
                                const int* __restrict__ ssrc, int base, int lane) {
    int s0 = ssrc[base + 0], s1 = ssrc[base + 1];
    int s2 = ssrc[base + 2], s3 = ssrc[base + 3];
    float v0 = bf2f(hhat[((size_t)s0 << 6) + lane]);
    float v1 = bf2f(hhat[((size_t)s1 << 6) + lane]);
    float v2 = bf2f(hhat[((size_t)s2 << 6) + lane]);
    float v3 = bf2f(hhat[((size_t)s3 << 6) + lane]);
    return (v0 + v1) + (v2 + v3);
}

__global__ __launch_bounds__(BLK) void k_zero(int* __restrict__ p, int n) {
    int i = blockIdx.x * BLK + threadIdx.x;
    if (i < n) p[i] = 0;
}

// ---- stage 1: single-pass partition into fixed bucket regions --------------
__global__ __launch_bounds__(BLK) void k_part(const int* __restrict__ src,
                                              const int* __restrict__ dst,
                                              int* __restrict__ bcnt,
                                              unsigned* __restrict__ packed,
                                              int e, int nb) {
    __shared__ int sdst[PCHUNK];   // 32 KB
    __shared__ int hist[1024];
    __shared__ int base[1024];
    int t = threadIdx.x;
    int chunk0 = blockIdx.x * PCHUNK;
    if (chunk0 >= e) return;
    int lim = min(PCHUNK, e - chunk0);
    int lim4 = lim >> 2;
    for (int i = t; i < nb; i += BLK) hist[i] = 0;
    __syncthreads();
    const int4* d4 = (const int4*)(dst + chunk0);
    for (int i = t; i < lim4; i += BLK) {
        int4 d = d4[i];
        ((int4*)sdst)[i] = d;
        atomicAdd(&hist[d.x >> 8], 1);
        atomicAdd(&hist[d.y >> 8], 1);
        atomicAdd(&hist[d.z >> 8], 1);
        atomicAdd(&hist[d.w >> 8], 1);
    }
    for (int i = (lim4 << 2) + t; i < lim; i += BLK) {
        int d = dst[chunk0 + i];
        sdst[i] = d;
        atomicAdd(&hist[d >> 8], 1);
    }
    __syncthreads();
    for (int i = t; i < nb; i += BLK) {
        int c = hist[i];
        base[i] = c ? (i * STRIDE + atomicAdd(&bcnt[i * CPAD], c)) : 0;
        hist[i] = 0;  // reuse as within-chunk cursor
    }
    __syncthreads();
    const int4* s4 = (const int4*)(src + chunk0);
    for (int i = t; i < lim4; i += BLK) {
        int4 d = ((int4*)sdst)[i];
        int4 s = s4[i];
        int b0 = d.x >> 8, b1 = d.y >> 8, b2 = d.z >> 8, b3 = d.w >> 8;
        int r0 = atomicAdd(&hist[b0], 1);
        packed[base[b0] + r0] = ((unsigned)s.x << 8) | (unsigned)(d.x & 255);
        int r1 = atomicAdd(&hist[b1], 1);
        packed[base[b1] + r1] = ((unsigned)s.y << 8) | (unsigned)(d.y & 255);
        int r2 = atomicAdd(&hist[b2], 1);
        packed[base[b2] + r2] = ((unsigned)s.z << 8) | (unsigned)(d.z & 255);
        int r3 = atomicAdd(&hist[b3], 1);
        packed[base[b3] + r3] = ((unsigned)s.w << 8) | (unsigned)(d.w & 255);
    }
    for (int i = (lim4 << 2) + t; i < lim; i += BLK) {
        int d = sdst[i];
        int b = d >> 8;
        int r = atomicAdd(&hist[b], 1);
        packed[base[b] + r] = ((unsigned)src[chunk0 + i] << 8) | (unsigned)(d & 255);
    }
}

// ---- stage 2: per-bucket LDS-staged counting sort -> padded CSR + dinv -----
__global__ __launch_bounds__(512) void k_sort(const unsigned* __restrict__ packed,
                                              const int* __restrict__ bcnt,
                                              int* __restrict__ ssrc,
                                              int* __restrict__ rowbeg,
                                              int* __restrict__ rowcnt,
                                              float* __restrict__ dinv, int n) {
    __shared__ unsigned sp[STRIDE];   // 20 KB bucket staging
    __shared__ int cnt[NPB];
    __shared__ int offs[NPB];
    int b = blockIdx.x;
    int t = threadIdx.x;
    int regionBase = b * STRIDE;
    int ecnt = bcnt[b * CPAD];
    if (t < NPB) cnt[t] = 0;
    __syncthreads();
    for (int i = t; i < ecnt; i += 512) {
        unsigned p = packed[regionBase + i];
        sp[i] = p;
        atomicAdd(&cnt[p & 255u], 1);
    }
    __syncthreads();
    if (t < NPB) offs[t] = cnt[t];
    __syncthreads();
    for (int off = 1; off < NPB; off <<= 1) {
        int x = 0;
        if (t < NPB && t >= off) x = offs[t - off];
        __syncthreads();
        if (t < NPB) offs[t] += x;
        __syncthreads();
    }
    int myoff = 0;
    if (t < NPB) {
        int v = cnt[t];
        myoff = offs[t] - v;  // exclusive
        int node = (b << 8) + t;
        if (node < n) {
            rowbeg[node] = regionBase + myoff;
            rowcnt[node] = v;
            dinv[node] = rsqrtf((float)(v + 1));   // +1 self-loop
        }
    }
    __syncthreads();
    if (t < NPB) cnt[t] = regionBase + myoff;  // reuse as cursor
    __syncthreads();
    for (int i = t; i < ecnt; i += 512) {
        unsigned p = sp[i];
        int pos = atomicAdd(&cnt[p & 255u], 1);
        ssrc[pos] = (int)(p >> 8);
    }
}

// ---- layer kernels ---------------------------------------------------------

// hhat[n][c] = bf16( dinv[n] * sum_k x[n][k]*W1[k][c] )
// thread = 4 nodes x 16 channels; straight-line form (round-7 verified).
__global__ __launch_bounds__(BLK) void k_gemm1(const float* __restrict__ x,
                                               const float* __restrict__ W1,
                                               const float* __restrict__ dinv,
                                               unsigned short* __restrict__ hhat, int n) {
    __shared__ float W[64 * 64];
    int t = threadIdx.x;
    #pragma unroll
    for (int i = 0; i < 16; ++i) W[t + BLK * i] = W1[t + BLK * i];
    __syncthreads();
    const int cg = t & 3;
    const int ng = t >> 2;
    const int node0 = blockIdx.x * 256 + ng * 4;
    const float* Wc = W + cg * 16;

    int nd[4];
    #pragma unroll
    for (int i = 0; i < 4; ++i) {
        int v = node0 + i;
        nd[i] = (v < n) ? v : (n - 1);
    }

    float4 acc[4][4];
    #pragma unroll
    for (int i = 0; i < 4; ++i)
        #pragma unroll
        for (int c = 0; c < 4; ++c) acc[i][c] = make_float4(0.f, 0.f, 0.f, 0.f);

    for (int k4 = 0; k4 < 16; ++k4) {
        float4 xv[4];
        #pragma unroll
        for (int i = 0; i < 4; ++i)
            xv[i] = ((const float4*)(x + (size_t)nd[i] * 64))[k4];
        #pragma unroll
        for (int kk = 0; kk < 4; ++kk) {
            const float4* wr = (const float4*)(Wc + (k4 * 4 + kk) * 64);
            float4 w0 = wr[0], w1 = wr[1], w2 = wr[2], w3 = wr[3];
            #pragma unroll
            for (int i = 0; i < 4; ++i) {
                float xa[4] = {xv[i].x, xv[i].y, xv[i].z, xv[i].w};
                float xs = xa[kk];
                acc[i][0].x = fmaf(xs, w0.x, acc[i][0].x);
                acc[i][0].y = fmaf(xs, w0.y, acc[i][0].y);
                acc[i][0].z = fmaf(xs, w0.z, acc[i][0].z);
                acc[i][0].w = fmaf(xs, w0.w, acc[i][0].w);
                acc[i][1].x = fmaf(xs, w1.x, acc[i][1].x);
                acc[i][1].y = fmaf(xs, w1.y, acc[i][1].y);
                acc[i][1].z = fmaf(xs, w1.z, acc[i][1].z);
                acc[i][1].w = fmaf(xs, w1.w, acc[i][1].w);
                acc[i][2].x = fmaf(xs, w2.x, acc[i][2].x);
                acc[i][2].y = fmaf(xs, w2.y, acc[i][2].y);
                acc[i][2].z = fmaf(xs, w2.z, acc[i][2].z);
                acc[i][2].w = fmaf(xs, w2.w, acc[i][2].w);
                acc[i][3].x = fmaf(xs, w3.x, acc[i][3].x);
                acc[i][3].y = fmaf(xs, w3.y, acc[i][3].y);
                acc[i][3].z = fmaf(xs, w3.z, acc[i][3].z);
                acc[i][3].w = fmaf(xs, w3.w, acc[i][3].w);
            }
        }
    }
    #pragma unroll
    for (int i = 0; i < 4; ++i) {
        int v = node0 + i;
        if (v < n) {
            float d = dinv[v];
            unsigned u0 = pack2bf(acc[i][0].x * d, acc[i][0].y * d);
            unsigned u1 = pack2bf(acc[i][0].z * d, acc[i][0].w * d);
            unsigned u2 = pack2bf(acc[i][1].x * d, acc[i][1].y * d);
            unsigned u3 = pack2bf(acc[i][1].z * d, acc[i][1].w * d);
            unsigned u4 = pack2bf(acc[i][2].x * d, acc[i][2].y * d);
            unsigned u5 = pack2bf(acc[i][2].z * d, acc[i][2].w * d);
            unsigned u6 = pack2bf(acc[i][3].x * d, acc[i][3].y * d);
            unsigned u7 = pack2bf(acc[i][3].z * d, acc[i][3].w * d);
            uint4* dst = (uint4*)(hhat + (size_t)v * 64 + cg * 16);
            dst[0] = make_uint4(u0, u1, u2, u3);
            dst[1] = make_uint4(u4, u5, u6, u7);
        }
    }
}

// QUAD-node wave: nodes 4w..4w+3, lane = channel (64). Interleaved 8-edge
// batches (up to 32 gathers in flight). All metadata/index loads wave-uniform.
// Fused layer-2 GEMV epilogue per node.
__global__ __launch_bounds__(BLK) void k_agg1(const unsigned short* __restrict__ hhat,
                                              const int* __restrict__ rowbeg,
                                              const int* __restrict__ rowcnt,
                                              const int* __restrict__ ssrc,
                                              const float* __restrict__ dinv,
                                              const float* __restrict__ b1,
                                              const float* __restrict__ W2,
                                              unsigned short* __restrict__ h2hat, int n) {
    int quad = __builtin_amdgcn_readfirstlane(
        (int)((blockIdx.x * BLK + threadIdx.x) >> 6));
    int lane = threadIdx.x & 63;
    int w0 = quad << 2;
    if (w0 >= n) return;
    const int g = lane >> 4;   // c-group for the fused GEMV
    const int j = lane & 15;   // output channel for the fused GEMV
    float w2r[16];
    #pragma unroll
    for (int k = 0; k < 16; ++k) w2r[k] = W2[(g * 16 + k) * 16 + j];

    int beg[4], cnt[4], e[4];
    float a[4];
    #pragma unroll
    for (int i = 0; i < 4; ++i) {
        int w = w0 + i;
        bool v = (w < n);
        beg[i] = v ? rowbeg[w] : 0;
        cnt[i] = v ? rowcnt[w] : 0;
        a[i] = v ? bf2f(hhat[((size_t)w << 6) + lane]) : 0.f;  // self-loop
        e[i] = 0;
    }
    // 4-way interleaved main: up to 32 gathers in flight
    while (e[0] + 8 <= cnt[0] && e[1] + 8 <= cnt[1] &&
           e[2] + 8 <= cnt[2] && e[3] + 8 <= cnt[3]) {
        float r0 = gather8(hhat, ssrc, beg[0] + e[0], lane);
        float r1 = gather8(hhat, ssrc, beg[1] + e[1], lane);
        float r2 = gather8(hhat, ssrc, beg[2] + e[2], lane);
        float r3 = gather8(hhat, ssrc, beg[3] + e[3], lane);
        a[0] += r0; a[1] += r1; a[2] += r2; a[3] += r3;
        e[0] += 8; e[1] += 8; e[2] += 8; e[3] += 8;
    }
    // 2-way interleaved drains
    while (e[0] + 8 <= cnt[0] && e[1] + 8 <= cnt[1]) {
        float r0 = gather8(hhat, ssrc, beg[0] + e[0], lane);
        float r1 = gather8(hhat, ssrc, beg[1] + e[1], lane);
        a[0] += r0; a[1] += r1; e[0] += 8; e[1] += 8;
    }
    while (e[2] + 8 <= cnt[2] && e[3] + 8 <= cnt[3]) {
        float r2 = gather8(hhat, ssrc, beg[2] + e[2], lane);
        float r3 = gather8(hhat, ssrc, beg[3] + e[3], lane);
        a[2] += r2; a[3] += r3; e[2] += 8; e[3] += 8;
    }
    #pragma unroll
    for (int i = 0; i < 4; ++i) {
        for (; e[i] + 8 <= cnt[i]; e[i] += 8)
            a[i] += gather8(hhat, ssrc, beg[i] + e[i], lane);
        if (e[i] + 4 <= cnt[i]) {
            a[i] += gather4(hhat, ssrc, beg[i] + e[i], lane);
            e[i] += 4;
        }
        for (; e[i] < cnt[i]; ++e[i])
            a[i] += bf2f(hhat[((size_t)ssrc[beg[i] + e[i]] << 6) + lane]);
    }
    // fused GEMV epilogues
    #pragma unroll
    for (int i = 0; i < 4; ++i) {
        int w = w0 + i;
        if (w < n) {
            float dv = dinv[w];
            float h = fmaxf(fmaf(dv, a[i], b1[lane]), 0.f);
            float part = 0.f;
            #pragma unroll
            for (int k = 0; k < 16; ++k)
                part = fmaf(__shfl(h, g * 16 + k, 64), w2r[k], part);
            part += __shfl_xor(part, 16, 64);
            part += __shfl_xor(part, 32, 64);
            if (g == 0) h2hat[(size_t)w * 16 + j] = f2bf(part * dv);
        }
    }
}

// DUAL-node wave layer 2: nodes 2w, 2w+1; 64 lanes = 4 edge-slots x 16 ch;
// uniform ssrc loads + cndmask select by slot; interleaved 8-edge batches.
__global__ __launch_bounds__(BLK) void k_agg2(const unsigned short* __restrict__ h2,
                                              const int* __restrict__ rowbeg,
                                              const int* __restrict__ rowcnt,
                                              const int* __restrict__ ssrc,
                                              const float* __restrict__ dinv,
                                              const float* __restrict__ b2,
                                              float* __restrict__ out, int n) {
    int pair = __builtin_amdgcn_readfirstlane(
        (int)((blockIdx.x * BLK + threadIdx.x) >> 6));
    int lane = threadIdx.x & 63;
    int w0 = pair << 1;
    if (w0 >= n) return;
    int w1 = w0 + 1;
    bool has1 = (w1 < n);
    int q = lane >> 4;      // edge slot 0..3
    int c = lane & 15;      // channel
    int beg0 = rowbeg[w0], cnt0 = rowcnt[w0];
    int beg1 = 0, cnt1 = 0;
    if (has1) { beg1 = rowbeg[w1]; cnt1 = rowcnt[w1]; }
    float a0 = 0.f, a1 = 0.f;
    int e0 = 0, e1 = 0;
    while (e0 + 8 <= cnt0 && e1 + 8 <= cnt1) {
        int p0 = beg0 + e0, p1 = beg1 + e1;
        int x0 = ssrc[p0 + 0], x1 = ssrc[p0 + 1], x2 = ssrc[p0 + 2], x3 = ssrc[p0 + 3];
        int x4 = ssrc[p0 + 4], x5 = ssrc[p0 + 5], x6 = ssrc[p0 + 6], x7 = ssrc[p0 + 7];
        int y0 = ssrc[p1 + 0], y1 = ssrc[p1 + 1], y2 = ssrc[p1 + 2], y3 = ssrc[p1 + 3];
        int y4 = ssrc[p1 + 4], y5 = ssrc[p1 + 5], y6 = ssrc[p1 + 6], y7 = ssrc[p1 + 7];
        int sA0 = sel4(x0, x1, x2, x3, q), sB0 = sel4(x4, x5, x6, x7, q);
        int sA1 = sel4(y0, y1, y2, y3, q), sB1 = sel4(y4, y5, y6, y7, q);
        float vA0 = bf2f(h2[((size_t)sA0 << 4) + c]);
        float vB0 = bf2f(h2[((size_t)sB0 << 4) + c]);
        float vA1 = bf2f(h2[((size_t)sA1 << 4) + c]);
        float vB1 = bf2f(h2[((size_t)sB1 << 4) + c]);
        a0 += vA0 + vB0;
        a1 += vA1 + vB1;
        e0 += 8; e1 += 8;
    }
    // drain node 0
    for (; e0 + 8 <= cnt0; e0 += 8) {
        int p0 = beg0 + e0;
        int x0 = ssrc[p0 + 0], x1 = ssrc[p0 + 1], x2 = ssrc[p0 + 2], x3 = ssrc[p0 + 3];
        int x4 = ssrc[p0 + 4], x5 = ssrc[p0 + 5], x6 = ssrc[p0 + 6], x7 = ssrc[p0 + 7];
        int sA = sel4(x0, x1, x2, x3, q), sB = sel4(x4, x5, x6, x7, q);
        a0 += bf2f(h2[((size_t)sA << 4) + c]) + bf2f(h2[((size_t)sB << 4) + c]);
    }
    if (e0 + 4 <= cnt0) {
        int p0 = beg0 + e0;
        int x0 = ssrc[p0 + 0], x1 = ssrc[p0 + 1], x2 = ssrc[p0 + 2], x3 = ssrc[p0 + 3];
        a0 += bf2f(h2[((size_t)sel4(x0, x1, x2, x3, q) << 4) + c]);
        e0 += 4;
    }
    if (e0 + q < cnt0)
        a0 += bf2f(h2[((size_t)ssrc[beg0 + e0 + q] << 4) + c]);
    // drain node 1
    for (; e1 + 8 <= cnt1; e1 += 8) {
        int p1 = beg1 + e1;
        int y0 = ssrc[p1 + 0], y1 = ssrc[p1 + 1], y2 = ssrc[p1 + 2], y3 = ssrc[p1 + 3];
        int y4 = ssrc[p1 + 4], y5 = ssrc[p1 + 5], y6 = ssrc[p1 + 6], y7 = ssrc[p1 + 7];
        int sA = sel4(y0, y1, y2, y3, q), sB = sel4(y4, y5, y6, y7, q);
        a1 += bf2f(h2[((size_t)sA << 4) + c]) + bf2f(h2[((size_t)sB << 4) + c]);
    }
    if (has1 && e1 + 4 <= cnt1) {
        int p1 = beg1 + e1;
        int y0 = ssrc[p1 + 0], y1 = ssrc[p1 + 1], y2 = ssrc[p1 + 2], y3 = ssrc[p1 + 3];
        a1 += bf2f(h2[((size_t)sel4(y0, y1, y2, y3, q) << 4) + c]);
        e1 += 4;
    }
    if (has1 && e1 + q < cnt1)
        a1 += bf2f(h2[((size_t)ssrc[beg1 + e1 + q] << 4) + c]);

    a0 += __shfl_xor(a0, 16, 64);
    a0 += __shfl_xor(a0, 32, 64);
    a1 += __shfl_xor(a1, 16, 64);
    a1 += __shfl_xor(a1, 32, 64);
    if (q == 0) {
        float self0 = bf2f(h2[((size_t)w0 << 4) + c]);
        out[((size_t)w0 << 4) + c] = fmaf(dinv[w0], a0 + self0, b2[c]);
        if (has1) {
            float self1 = bf2f(h2[((size_t)w1 << 4) + c]);
            out[((size_t)w1 << 4) + c] = fmaf(dinv[w1], a1 + self1, b2[c]);
        }
    }
}

} // namespace

extern "C" void kernel_launch(void* const* d_in, const int* in_sizes, int n_in,
                              void* d_out, int out_size, void* d_ws, size_t ws_size,
                              hipStream_t stream) {
    const float* x  = (const float*)d_in[0];
    const int*   ei = (const int*)d_in[1];
    const float* W1 = (const float*)d_in[2];
    const float* b1 = (const float*)d_in[3];
    const float* W2 = (const float*)d_in[4];
    const float* b2 = (const float*)d_in[5];
    float* out = (float*)d_out;

    const int N = in_sizes[0] / 64;
    const int E = in_sizes[1] / 2;
    const int* src = ei;
    const int* dst = ei + E;
    const int nb = (N + NPB - 1) / NPB;   // buckets (<=1024)

    char* ws = (char*)d_ws;
    size_t off = 0;
    auto alloc = [&](size_t bytes) -> char* {
        char* p = ws + off;
        off = (off + bytes + 255) & ~(size_t)255;
        return p;
    };
    int*            bcnt   = (int*)alloc((size_t)1024 * CPAD * 4);
    int*            rowbeg = (int*)alloc((size_t)N * 4);
    int*            rowcnt = (int*)alloc((size_t)N * 4);
    float*          dinv   = (float*)alloc((size_t)N * 4);
    unsigned*       packed = (unsigned*)alloc((size_t)nb * STRIDE * 4);
    int*            ssrc   = (int*)alloc((size_t)nb * STRIDE * 4);
    unsigned short* hhat   = (unsigned short*)alloc((size_t)N * 64 * 2);
    unsigned short* h2hat  = (unsigned short*)alloc((size_t)N * 16 * 2);

    const int nb_n = (N + BLK - 1) / BLK;
    const int nchunks = (E + PCHUNK - 1) / PCHUNK;
    const int nquads = (N + 3) / 4;
    const int npairs = (N + 1) / 2;
    const int nb_q = (int)(((long long)nquads * 64 + BLK - 1) / BLK);  // quad-node
    const int nb_p = (int)(((long long)npairs * 64 + BLK - 1) / BLK);  // dual-node

    const int zn = nb * CPAD;
    k_zero<<<(zn + BLK - 1) / BLK, BLK, 0, stream>>>(bcnt, zn);
    k_part<<<nchunks, BLK, 0, stream>>>(src, dst, bcnt, packed, E, nb);
    k_sort<<<nb, 512, 0, stream>>>(packed, bcnt, ssrc, rowbeg, rowcnt, dinv, N);

    k_gemm1<<<nb_n, BLK, 0, stream>>>(x, W1, dinv, hhat, N);
    k_agg1<<<nb_q, BLK, 0, stream>>>(hhat, rowbeg, rowcnt, ssrc, dinv, b1, W2,
                                     h2hat, N);
    k_agg2<<<nb_p, BLK, 0, stream>>>(h2hat, rowbeg, rowcnt, ssrc, dinv, b2, out, N);
}

// Round 13
// 210.830 us; speedup vs baseline: 1.4675x; 1.0265x over previous
//
#include <hip/hip_runtime.h>

// 2-layer GCN. zero -> part (bucket partition, padded counters, no LDS
// staging) -> sort (LDS-staged per-bucket counting sort) -> gemm1 ->
// agg1 (dual-node waves, fused layer-2 GEMV) -> agg2 (dual-node waves).
// Edge-index loads kept wave-uniform (scalar cache) in both agg kernels;
// feature gathers are 64-lane ushort (bf16) with fp32 accumulation.
// Lessons: ch-blocking (r11) and quad-node (r12) both regress; dual-node is
// the MLP/occupancy equilibrium. FETCH ~86MB is the per-XCD compulsory floor.

namespace {
constexpr int BLK = 256;
constexpr int NPB = 256;       // nodes per bucket (dstLocal fits in 8 bits)
constexpr int PCHUNK = 8192;   // edges per partition block
constexpr int STRIDE = 5120;   // padded region per bucket: mean 4096 + 16 sigma
constexpr int CPAD = 32;       // bcnt padding: 1 counter per 128 B line

__device__ inline float bf2f(unsigned short h) {
    union { unsigned u; float f; } v; v.u = (unsigned)h << 16; return v.f;
}
__device__ inline unsigned short f2bf(float f) {
    union { float f; unsigned u; } v; v.f = f;
    unsigned r = (v.u + 0x7FFFu + ((v.u >> 16) & 1u)) >> 16;  // RNE
    return (unsigned short)r;
}
__device__ inline unsigned pack2bf(float a, float b) {
    return (unsigned)f2bf(a) | ((unsigned)f2bf(b) << 16);
}
// select one of 4 scalar edge ids by lane slot q (0..3) — cndmask tree
__device__ inline int sel4(int s0, int s1, int s2, int s3, int q) {
    int sa = (q & 1) ? s1 : s0;
    int sb = (q & 1) ? s3 : s2;
    return (q & 2) ? sb : sa;
}

// 8 / 4-edge gather helpers (indices wave-uniform -> scalar cache)
__device__ inline float gather8(const unsigned short* __restrict__ hhat,
                                const int* __restrict__ ssrc, int base, int lane) {
    int s0 = ssrc[base + 0], s1 = ssrc[base + 1];
    int s2 = ssrc[base + 2], s3 = ssrc[base + 3];
    int s4 = ssrc[base + 4], s5 = ssrc[base + 5];
    int s6 = ssrc[base + 6], s7 = ssrc[base + 7];
    float v0 = bf2f(hhat[((size_t)s0 << 6) + lane]);
    float v1 = bf2f(hhat[((size_t)s1 << 6) + lane]);
    float v2 = bf2f(hhat[((size_t)s2 << 6) + lane]);
    float v3 = bf2f(hhat[((size_t)s3 << 6) + lane]);
    float v4 = bf2f(hhat[((size_t)s4 << 6) + lane]);
    float v5 = bf2f(hhat[((size_t)s5 << 6) + lane]);
    float v6 = bf2f(hhat[((size_t)s6 << 6) + lane]);
    float v7 = bf2f(hhat[((size_t)s7 << 6) + lane]);
    return ((v0 + v1) + (v2 + v3)) + ((v4 + v5) + (v6 + v7));
}
__device__ inline float gather4(const unsigned short* __restrict__ hhat,
                                const int* __restrict__ ssrc, int base, int lane) {
    int s0 = ssrc[base + 0], s1 = ssrc[base + 1];
    int s2 = ssrc[base + 2], s3 = ssrc[base + 3];
    float v0 = bf2f(hhat[((size_t)s0 << 6) + lane]);
    float v1 = bf2f(hhat[((size_t)s1 << 6) + lane]);
    float v2 = bf2f(hhat[((size_t)s2 << 6) + lane]);
    float v3 = bf2f(hhat[((size_t)s3 << 6) + lane]);
    return (v0 + v1) + (v2 + v3);
}

__global__ __launch_bounds__(BLK) void k_zero(int* __restrict__ p, int n) {
    int i = blockIdx.x * BLK + threadIdx.x;
    if (i < n) p[i] = 0;
}

// ---- stage 1: single-pass partition into fixed bucket regions --------------
// No LDS staging: dst is re-read in pass 2 (coalesced, L2-hot). LDS = 8 KB.
__global__ __launch_bounds__(BLK) void k_part(const int* __restrict__ src,
                                              const int* __restrict__ dst,
                                              int* __restrict__ bcnt,
                                              unsigned* __restrict__ packed,
                                              int e, int nb) {
    __shared__ int hist[1024];
    __shared__ int base[1024];
    int t = threadIdx.x;
    int chunk0 = blockIdx.x * PCHUNK;
    if (chunk0 >= e) return;
    int lim = min(PCHUNK, e - chunk0);
    int lim4 = lim >> 2;
    for (int i = t; i < nb; i += BLK) hist[i] = 0;
    __syncthreads();
    const int4* d4 = (const int4*)(dst + chunk0);
    for (int i = t; i < lim4; i += BLK) {
        int4 d = d4[i];
        atomicAdd(&hist[d.x >> 8], 1);
        atomicAdd(&hist[d.y >> 8], 1);
        atomicAdd(&hist[d.z >> 8], 1);
        atomicAdd(&hist[d.w >> 8], 1);
    }
    for (int i = (lim4 << 2) + t; i < lim; i += BLK)
        atomicAdd(&hist[dst[chunk0 + i] >> 8], 1);
    __syncthreads();
    for (int i = t; i < nb; i += BLK) {
        int c = hist[i];
        base[i] = c ? (i * STRIDE + atomicAdd(&bcnt[i * CPAD], c)) : 0;
        hist[i] = 0;  // reuse as within-chunk cursor
    }
    __syncthreads();
    const int4* s4 = (const int4*)(src + chunk0);
    for (int i = t; i < lim4; i += BLK) {
        int4 d = d4[i];
        int4 s = s4[i];
        int b0 = d.x >> 8, b1 = d.y >> 8, b2 = d.z >> 8, b3 = d.w >> 8;
        int r0 = atomicAdd(&hist[b0], 1);
        packed[base[b0] + r0] = ((unsigned)s.x << 8) | (unsigned)(d.x & 255);
        int r1 = atomicAdd(&hist[b1], 1);
        packed[base[b1] + r1] = ((unsigned)s.y << 8) | (unsigned)(d.y & 255);
        int r2 = atomicAdd(&hist[b2], 1);
        packed[base[b2] + r2] = ((unsigned)s.z << 8) | (unsigned)(d.z & 255);
        int r3 = atomicAdd(&hist[b3], 1);
        packed[base[b3] + r3] = ((unsigned)s.w << 8) | (unsigned)(d.w & 255);
    }
    for (int i = (lim4 << 2) + t; i < lim; i += BLK) {
        int d = dst[chunk0 + i];
        int b = d >> 8;
        int r = atomicAdd(&hist[b], 1);
        packed[base[b] + r] = ((unsigned)src[chunk0 + i] << 8) | (unsigned)(d & 255);
    }
}

// ---- stage 2: per-bucket LDS-staged counting sort -> padded CSR + dinv -----
__global__ __launch_bounds__(512) void k_sort(const unsigned* __restrict__ packed,
                                              const int* __restrict__ bcnt,
                                              int* __restrict__ ssrc,
                                              int* __restrict__ rowbeg,
                                              int* __restrict__ rowcnt,
                                              float* __restrict__ dinv, int n) {
    __shared__ unsigned sp[STRIDE];   // 20 KB bucket staging
    __shared__ int cnt[NPB];
    __shared__ int offs[NPB];
    int b = blockIdx.x;
    int t = threadIdx.x;
    int regionBase = b * STRIDE;
    int ecnt = bcnt[b * CPAD];
    if (t < NPB) cnt[t] = 0;
    __syncthreads();
    for (int i = t; i < ecnt; i += 512) {
        unsigned p = packed[regionBase + i];
        sp[i] = p;
        atomicAdd(&cnt[p & 255u], 1);
    }
    __syncthreads();
    if (t < NPB) offs[t] = cnt[t];
    __syncthreads();
    for (int off = 1; off < NPB; off <<= 1) {
        int x = 0;
        if (t < NPB && t >= off) x = offs[t - off];
        __syncthreads();
        if (t < NPB) offs[t] += x;
        __syncthreads();
    }
    int myoff = 0;
    if (t < NPB) {
        int v = cnt[t];
        myoff = offs[t] - v;  // exclusive
        int node = (b << 8) + t;
        if (node < n) {
            rowbeg[node] = regionBase + myoff;
            rowcnt[node] = v;
            dinv[node] = rsqrtf((float)(v + 1));   // +1 self-loop
        }
    }
    __syncthreads();
    if (t < NPB) cnt[t] = regionBase + myoff;  // reuse as cursor
    __syncthreads();
    for (int i = t; i < ecnt; i += 512) {
        unsigned p = sp[i];
        int pos = atomicAdd(&cnt[p & 255u], 1);
        ssrc[pos] = (int)(p >> 8);
    }
}

// ---- layer kernels ---------------------------------------------------------

// hhat[n][c] = bf16( dinv[n] * sum_k x[n][k]*W1[k][c] )
// thread = 4 nodes x 16 channels; straight-line form (round-7 verified).
__global__ __launch_bounds__(BLK) void k_gemm1(const float* __restrict__ x,
                                               const float* __restrict__ W1,
                                               const float* __restrict__ dinv,
                                               unsigned short* __restrict__ hhat, int n) {
    __shared__ float W[64 * 64];
    int t = threadIdx.x;
    #pragma unroll
    for (int i = 0; i < 16; ++i) W[t + BLK * i] = W1[t + BLK * i];
    __syncthreads();
    const int cg = t & 3;
    const int ng = t >> 2;
    const int node0 = blockIdx.x * 256 + ng * 4;
    const float* Wc = W + cg * 16;

    int nd[4];
    #pragma unroll
    for (int i = 0; i < 4; ++i) {
        int v = node0 + i;
        nd[i] = (v < n) ? v : (n - 1);
    }

    float4 acc[4][4];
    #pragma unroll
    for (int i = 0; i < 4; ++i)
        #pragma unroll
        for (int c = 0; c < 4; ++c) acc[i][c] = make_float4(0.f, 0.f, 0.f, 0.f);

    for (int k4 = 0; k4 < 16; ++k4) {
        float4 xv[4];
        #pragma unroll
        for (int i = 0; i < 4; ++i)
            xv[i] = ((const float4*)(x + (size_t)nd[i] * 64))[k4];
        #pragma unroll
        for (int kk = 0; kk < 4; ++kk) {
            const float4* wr = (const float4*)(Wc + (k4 * 4 + kk) * 64);
            float4 w0 = wr[0], w1 = wr[1], w2 = wr[2], w3 = wr[3];
            #pragma unroll
            for (int i = 0; i < 4; ++i) {
                float xa[4] = {xv[i].x, xv[i].y, xv[i].z, xv[i].w};
                float xs = xa[kk];
                acc[i][0].x = fmaf(xs, w0.x, acc[i][0].x);
                acc[i][0].y = fmaf(xs, w0.y, acc[i][0].y);
                acc[i][0].z = fmaf(xs, w0.z, acc[i][0].z);
                acc[i][0].w = fmaf(xs, w0.w, acc[i][0].w);
                acc[i][1].x = fmaf(xs, w1.x, acc[i][1].x);
                acc[i][1].y = fmaf(xs, w1.y, acc[i][1].y);
                acc[i][1].z = fmaf(xs, w1.z, acc[i][1].z);
                acc[i][1].w = fmaf(xs, w1.w, acc[i][1].w);
                acc[i][2].x = fmaf(xs, w2.x, acc[i][2].x);
                acc[i][2].y = fmaf(xs, w2.y, acc[i][2].y);
                acc[i][2].z = fmaf(xs, w2.z, acc[i][2].z);
                acc[i][2].w = fmaf(xs, w2.w, acc[i][2].w);
                acc[i][3].x = fmaf(xs, w3.x, acc[i][3].x);
                acc[i][3].y = fmaf(xs, w3.y, acc[i][3].y);
                acc[i][3].z = fmaf(xs, w3.z, acc[i][3].z);
                acc[i][3].w = fmaf(xs, w3.w, acc[i][3].w);
            }
        }
    }
    #pragma unroll
    for (int i = 0; i < 4; ++i) {
        int v = node0 + i;
        if (v < n) {
            float d = dinv[v];
            unsigned u0 = pack2bf(acc[i][0].x * d, acc[i][0].y * d);
            unsigned u1 = pack2bf(acc[i][0].z * d, acc[i][0].w * d);
            unsigned u2 = pack2bf(acc[i][1].x * d, acc[i][1].y * d);
            unsigned u3 = pack2bf(acc[i][1].z * d, acc[i][1].w * d);
            unsigned u4 = pack2bf(acc[i][2].x * d, acc[i][2].y * d);
            unsigned u5 = pack2bf(acc[i][2].z * d, acc[i][2].w * d);
            unsigned u6 = pack2bf(acc[i][3].x * d, acc[i][3].y * d);
            unsigned u7 = pack2bf(acc[i][3].z * d, acc[i][3].w * d);
            uint4* dst = (uint4*)(hhat + (size_t)v * 64 + cg * 16);
            dst[0] = make_uint4(u0, u1, u2, u3);
            dst[1] = make_uint4(u4, u5, u6, u7);
        }
    }
}

// DUAL-node wave: nodes 2w and 2w+1, lane = channel (64). Interleaved 8-edge
// batches (up to 16 gathers in flight). All metadata/index loads wave-uniform.
// Fused layer-2 GEMV epilogue per node. (round-10 verified champion)
__global__ __launch_bounds__(BLK) void k_agg1(const unsigned short* __restrict__ hhat,
                                              const int* __restrict__ rowbeg,
                                              const int* __restrict__ rowcnt,
                                              const int* __restrict__ ssrc,
                                              const float* __restrict__ dinv,
                                              const float* __restrict__ b1,
                                              const float* __restrict__ W2,
                                              unsigned short* __restrict__ h2hat, int n) {
    int pair = __builtin_amdgcn_readfirstlane(
        (int)((blockIdx.x * BLK + threadIdx.x) >> 6));
    int lane = threadIdx.x & 63;
    int wid0 = pair << 1;
    if (wid0 >= n) return;
    int wid1 = wid0 + 1;
    bool has1 = (wid1 < n);
    const int g = lane >> 4;   // c-group for the fused GEMV
    const int j = lane & 15;   // output channel for the fused GEMV
    float w2r[16];
    #pragma unroll
    for (int k = 0; k < 16; ++k) w2r[k] = W2[(g * 16 + k) * 16 + j];

    int beg0 = rowbeg[wid0], cnt0 = rowcnt[wid0];
    int beg1 = 0, cnt1 = 0;
    if (has1) { beg1 = rowbeg[wid1]; cnt1 = rowcnt[wid1]; }
    float a0 = bf2f(hhat[((size_t)wid0 << 6) + lane]);  // self-loop
    float a1 = 0.f;
    if (has1) a1 = bf2f(hhat[((size_t)wid1 << 6) + lane]);
    int e0 = 0, e1 = 0;
    // interleaved main: 16 gathers in flight
    while (e0 + 8 <= cnt0 && e1 + 8 <= cnt1) {
        float r0 = gather8(hhat, ssrc, beg0 + e0, lane);
        float r1 = gather8(hhat, ssrc, beg1 + e1, lane);
        a0 += r0;
        a1 += r1;
        e0 += 8; e1 += 8;
    }
    for (; e0 + 8 <= cnt0; e0 += 8) a0 += gather8(hhat, ssrc, beg0 + e0, lane);
    for (; e1 + 8 <= cnt1; e1 += 8) a1 += gather8(hhat, ssrc, beg1 + e1, lane);
    if (e0 + 4 <= cnt0) { a0 += gather4(hhat, ssrc, beg0 + e0, lane); e0 += 4; }
    if (e1 + 4 <= cnt1) { a1 += gather4(hhat, ssrc, beg1 + e1, lane); e1 += 4; }
    for (; e0 < cnt0; ++e0) a0 += bf2f(hhat[((size_t)ssrc[beg0 + e0] << 6) + lane]);
    for (; e1 < cnt1; ++e1) a1 += bf2f(hhat[((size_t)ssrc[beg1 + e1] << 6) + lane]);

    // fused GEMV epilogue, node 0
    {
        float dv = dinv[wid0];
        float h = fmaxf(fmaf(dv, a0, b1[lane]), 0.f);
        float part = 0.f;
        #pragma unroll
        for (int k = 0; k < 16; ++k)
            part = fmaf(__shfl(h, g * 16 + k, 64), w2r[k], part);
        part += __shfl_xor(part, 16, 64);
        part += __shfl_xor(part, 32, 64);
        if (g == 0) h2hat[(size_t)wid0 * 16 + j] = f2bf(part * dv);
    }
    if (has1) {
        float dv = dinv[wid1];
        float h = fmaxf(fmaf(dv, a1, b1[lane]), 0.f);
        float part = 0.f;
        #pragma unroll
        for (int k = 0; k < 16; ++k)
            part = fmaf(__shfl(h, g * 16 + k, 64), w2r[k], part);
        part += __shfl_xor(part, 16, 64);
        part += __shfl_xor(part, 32, 64);
        if (g == 0) h2hat[(size_t)wid1 * 16 + j] = f2bf(part * dv);
    }
}

// DUAL-node wave layer 2: nodes 2w, 2w+1; 64 lanes = 4 edge-slots x 16 ch;
// uniform ssrc loads + cndmask select by slot; interleaved 8-edge batches.
__global__ __launch_bounds__(BLK) void k_agg2(const unsigned short* __restrict__ h2,
                                              const int* __restrict__ rowbeg,
                                              const int* __restrict__ rowcnt,
                                              const int* __restrict__ ssrc,
                                              const float* __restrict__ dinv,
                                              const float* __restrict__ b2,
                                              float* __restrict__ out, int n) {
    int pair = __builtin_amdgcn_readfirstlane(
        (int)((blockIdx.x * BLK + threadIdx.x) >> 6));
    int lane = threadIdx.x & 63;
    int w0 = pair << 1;
    if (w0 >= n) return;
    int w1 = w0 + 1;
    bool has1 = (w1 < n);
    int q = lane >> 4;      // edge slot 0..3
    int c = lane & 15;      // channel
    int beg0 = rowbeg[w0], cnt0 = rowcnt[w0];
    int beg1 = 0, cnt1 = 0;
    if (has1) { beg1 = rowbeg[w1]; cnt1 = rowcnt[w1]; }
    float a0 = 0.f, a1 = 0.f;
    int e0 = 0, e1 = 0;
    while (e0 + 8 <= cnt0 && e1 + 8 <= cnt1) {
        int p0 = beg0 + e0, p1 = beg1 + e1;
        int x0 = ssrc[p0 + 0], x1 = ssrc[p0 + 1], x2 = ssrc[p0 + 2], x3 = ssrc[p0 + 3];
        int x4 = ssrc[p0 + 4], x5 = ssrc[p0 + 5], x6 = ssrc[p0 + 6], x7 = ssrc[p0 + 7];
        int y0 = ssrc[p1 + 0], y1 = ssrc[p1 + 1], y2 = ssrc[p1 + 2], y3 = ssrc[p1 + 3];
        int y4 = ssrc[p1 + 4], y5 = ssrc[p1 + 5], y6 = ssrc[p1 + 6], y7 = ssrc[p1 + 7];
        int sA0 = sel4(x0, x1, x2, x3, q), sB0 = sel4(x4, x5, x6, x7, q);
        int sA1 = sel4(y0, y1, y2, y3, q), sB1 = sel4(y4, y5, y6, y7, q);
        float vA0 = bf2f(h2[((size_t)sA0 << 4) + c]);
        float vB0 = bf2f(h2[((size_t)sB0 << 4) + c]);
        float vA1 = bf2f(h2[((size_t)sA1 << 4) + c]);
        float vB1 = bf2f(h2[((size_t)sB1 << 4) + c]);
        a0 += vA0 + vB0;
        a1 += vA1 + vB1;
        e0 += 8; e1 += 8;
    }
    // drain node 0
    for (; e0 + 8 <= cnt0; e0 += 8) {
        int p0 = beg0 + e0;
        int x0 = ssrc[p0 + 0], x1 = ssrc[p0 + 1], x2 = ssrc[p0 + 2], x3 = ssrc[p0 + 3];
        int x4 = ssrc[p0 + 4], x5 = ssrc[p0 + 5], x6 = ssrc[p0 + 6], x7 = ssrc[p0 + 7];
        int sA = sel4(x0, x1, x2, x3, q), sB = sel4(x4, x5, x6, x7, q);
        a0 += bf2f(h2[((size_t)sA << 4) + c]) + bf2f(h2[((size_t)sB << 4) + c]);
    }
    if (e0 + 4 <= cnt0) {
        int p0 = beg0 + e0;
        int x0 = ssrc[p0 + 0], x1 = ssrc[p0 + 1], x2 = ssrc[p0 + 2], x3 = ssrc[p0 + 3];
        a0 += bf2f(h2[((size_t)sel4(x0, x1, x2, x3, q) << 4) + c]);
        e0 += 4;
    }
    if (e0 + q < cnt0)
        a0 += bf2f(h2[((size_t)ssrc[beg0 + e0 + q] << 4) + c]);
    // drain node 1
    for (; e1 + 8 <= cnt1; e1 += 8) {
        int p1 = beg1 + e1;
        int y0 = ssrc[p1 + 0], y1 = ssrc[p1 + 1], y2 = ssrc[p1 + 2], y3 = ssrc[p1 + 3];
        int y4 = ssrc[p1 + 4], y5 = ssrc[p1 + 5], y6 = ssrc[p1 + 6], y7 = ssrc[p1 + 7];
        int sA = sel4(y0, y1, y2, y3, q), sB = sel4(y4, y5, y6, y7, q);
        a1 += bf2f(h2[((size_t)sA << 4) + c]) + bf2f(h2[((size_t)sB << 4) + c]);
    }
    if (has1 && e1 + 4 <= cnt1) {
        int p1 = beg1 + e1;
        int y0 = ssrc[p1 + 0], y1 = ssrc[p1 + 1], y2 = ssrc[p1 + 2], y3 = ssrc[p1 + 3];
        a1 += bf2f(h2[((size_t)sel4(y0, y1, y2, y3, q) << 4) + c]);
        e1 += 4;
    }
    if (has1 && e1 + q < cnt1)
        a1 += bf2f(h2[((size_t)ssrc[beg1 + e1 + q] << 4) + c]);

    a0 += __shfl_xor(a0, 16, 64);
    a0 += __shfl_xor(a0, 32, 64);
    a1 += __shfl_xor(a1, 16, 64);
    a1 += __shfl_xor(a1, 32, 64);
    if (q == 0) {
        float self0 = bf2f(h2[((size_t)w0 << 4) + c]);
        out[((size_t)w0 << 4) + c] = fmaf(dinv[w0], a0 + self0, b2[c]);
        if (has1) {
            float self1 = bf2f(h2[((size_t)w1 << 4) + c]);
            out[((size_t)w1 << 4) + c] = fmaf(dinv[w1], a1 + self1, b2[c]);
        }
    }
}

} // namespace

extern "C" void kernel_launch(void* const* d_in, const int* in_sizes, int n_in,
                              void* d_out, int out_size, void* d_ws, size_t ws_size,
                              hipStream_t stream) {
    const float* x  = (const float*)d_in[0];
    const int*   ei = (const int*)d_in[1];
    const float* W1 = (const float*)d_in[2];
    const float* b1 = (const float*)d_in[3];
    const float* W2 = (const float*)d_in[4];
    const float* b2 = (const float*)d_in[5];
    float* out = (float*)d_out;

    const int N = in_sizes[0] / 64;
    const int E = in_sizes[1] / 2;
    const int* src = ei;
    const int* dst = ei + E;
    const int nb = (N + NPB - 1) / NPB;   // buckets (<=1024)

    char* ws = (char*)d_ws;
    size_t off = 0;
    auto alloc = [&](size_t bytes) -> char* {
        char* p = ws + off;
        off = (off + bytes + 255) & ~(size_t)255;
        return p;
    };
    int*            bcnt   = (int*)alloc((size_t)1024 * CPAD * 4);
    int*            rowbeg = (int*)alloc((size_t)N * 4);
    int*            rowcnt = (int*)alloc((size_t)N * 4);
    float*          dinv   = (float*)alloc((size_t)N * 4);
    unsigned*       packed = (unsigned*)alloc((size_t)nb * STRIDE * 4);
    int*            ssrc   = (int*)alloc((size_t)nb * STRIDE * 4);
    unsigned short* hhat   = (unsigned short*)alloc((size_t)N * 64 * 2);
    unsigned short* h2hat  = (unsigned short*)alloc((size_t)N * 16 * 2);

    const int nb_n = (N + BLK - 1) / BLK;
    const int nchunks = (E + PCHUNK - 1) / PCHUNK;
    const int npairs = (N + 1) / 2;
    const int nb_p = (int)(((long long)npairs * 64 + BLK - 1) / BLK);  // dual-node

    const int zn = nb * CPAD;
    k_zero<<<(zn + BLK - 1) / BLK, BLK, 0, stream>>>(bcnt, zn);
    k_part<<<nchunks, BLK, 0, stream>>>(src, dst, bcnt, packed, E, nb);
    k_sort<<<nb, 512, 0, stream>>>(packed, bcnt, ssrc, rowbeg, rowcnt, dinv, N);

    k_gemm1<<<nb_n, BLK, 0, stream>>>(x, W1, dinv, hhat, N);
    k_agg1<<<nb_p, BLK, 0, stream>>>(hhat, rowbeg, rowcnt, ssrc, dinv, b1, W2,
                                     h2hat, N);
    k_agg2<<<nb_p, BLK, 0, stream>>>(h2hat, rowbeg, rowcnt, ssrc, dinv, b2, out, N);
}

// Round 14
// 200.148 us; speedup vs baseline: 1.5458x; 1.0534x over previous
//
#include <hip/hip_runtime.h>

// 2-layer GCN. zero -> part (bucket partition, padded counters) -> sort
// (4-way quarter-split per-bucket counting sort, 1564 blocks) -> gemm1
// (grid-stride persistent, 1024 blocks) -> agg1 (dual-node waves, fused
// layer-2 GEMV) -> agg2 (dual-node waves).
// Lessons: ch-blocking (r11) and quad-node (r12) regress; dual-node is the
// MLP/occupancy equilibrium; agg1 FETCH ~86MB is the per-XCD compulsory
// fabric floor (8 XCDs x ~11MB unique lines). This round attacks mid-tier
// occupancy: gemm1 had 1.5 waves/CU, sort had 1.5 blocks/CU.

namespace {
constexpr int BLK = 256;
constexpr int NPB = 256;       // nodes per bucket (dstLocal fits in 8 bits)
constexpr int PCHUNK = 8192;   // edges per partition block
constexpr int STRIDE = 5120;   // padded region per bucket: mean 4096 + 16 sigma
constexpr int CPAD = 32;       // bcnt padding: 1 counter per 128 B line

__device__ inline float bf2f(unsigned short h) {
    union { unsigned u; float f; } v; v.u = (unsigned)h << 16; return v.f;
}
__device__ inline unsigned short f2bf(float f) {
    union { float f; unsigned u; } v; v.f = f;
    unsigned r = (v.u + 0x7FFFu + ((v.u >> 16) & 1u)) >> 16;  // RNE
    return (unsigned short)r;
}
__device__ inline unsigned pack2bf(float a, float b) {
    return (unsigned)f2bf(a) | ((unsigned)f2bf(b) << 16);
}
// select one of 4 scalar edge ids by lane slot q (0..3) — cndmask tree
__device__ inline int sel4(int s0, int s1, int s2, int s3, int q) {
    int sa = (q & 1) ? s1 : s0;
    int sb = (q & 1) ? s3 : s2;
    return (q & 2) ? sb : sa;
}

// 8 / 4-edge gather helpers (indices wave-uniform -> scalar cache)
__device__ inline float gather8(const unsigned short* __restrict__ hhat,
                                const int* __restrict__ ssrc, int base, int lane) {
    int s0 = ssrc[base + 0], s1 = ssrc[base + 1];
    int s2 = ssrc[base + 2], s3 = ssrc[base + 3];
    int s4 = ssrc[base + 4], s5 = ssrc[base + 5];
    int s6 = ssrc[base + 6], s7 = ssrc[base + 7];
    float v0 = bf2f(hhat[((size_t)s0 << 6) + lane]);
    float v1 = bf2f(hhat[((size_t)s1 << 6) + lane]);
    float v2 = bf2f(hhat[((size_t)s2 << 6) + lane]);
    float v3 = bf2f(hhat[((size_t)s3 << 6) + lane]);
    float v4 = bf2f(hhat[((size_t)s4 << 6) + lane]);
    float v5 = bf2f(hhat[((size_t)s5 << 6) + lane]);
    float v6 = bf2f(hhat[((size_t)s6 << 6) + lane]);
    float v7 = bf2f(hhat[((size_t)s7 << 6) + lane]);
    return ((v0 + v1) + (v2 + v3)) + ((v4 + v5) + (v6 + v7));
}
__device__ inline float gather4(const unsigned short* __restrict__ hhat,
                                const int* __restrict__ ssrc, int base, int lane) {
    int s0 = ssrc[base + 0], s1 = ssrc[base + 1];
    int s2 = ssrc[base + 2], s3 = ssrc[base + 3];
    float v0 = bf2f(hhat[((size_t)s0 << 6) + lane]);
    float v1 = bf2f(hhat[((size_t)s1 << 6) + lane]);
    float v2 = bf2f(hhat[((size_t)s2 << 6) + lane]);
    float v3 = bf2f(hhat[((size_t)s3 << 6) + lane]);
    return (v0 + v1) + (v2 + v3);
}

__global__ __launch_bounds__(BLK) void k_zero(int* __restrict__ p, int n) {
    int i = blockIdx.x * BLK + threadIdx.x;
    if (i < n) p[i] = 0;
}

// ---- stage 1: single-pass partition into fixed bucket regions --------------
__global__ __launch_bounds__(BLK) void k_part(const int* __restrict__ src,
                                              const int* __restrict__ dst,
                                              int* __restrict__ bcnt,
                                              unsigned* __restrict__ packed,
                                              int e, int nb) {
    __shared__ int hist[1024];
    __shared__ int base[1024];
    int t = threadIdx.x;
    int chunk0 = blockIdx.x * PCHUNK;
    if (chunk0 >= e) return;
    int lim = min(PCHUNK, e - chunk0);
    int lim4 = lim >> 2;
    for (int i = t; i < nb; i += BLK) hist[i] = 0;
    __syncthreads();
    const int4* d4 = (const int4*)(dst + chunk0);
    for (int i = t; i < lim4; i += BLK) {
        int4 d = d4[i];
        atomicAdd(&hist[d.x >> 8], 1);
        atomicAdd(&hist[d.y >> 8], 1);
        atomicAdd(&hist[d.z >> 8], 1);
        atomicAdd(&hist[d.w >> 8], 1);
    }
    for (int i = (lim4 << 2) + t; i < lim; i += BLK)
        atomicAdd(&hist[dst[chunk0 + i] >> 8], 1);
    __syncthreads();
    for (int i = t; i < nb; i += BLK) {
        int c = hist[i];
        base[i] = c ? (i * STRIDE + atomicAdd(&bcnt[i * CPAD], c)) : 0;
        hist[i] = 0;  // reuse as within-chunk cursor
    }
    __syncthreads();
    const int4* s4 = (const int4*)(src + chunk0);
    for (int i = t; i < lim4; i += BLK) {
        int4 d = d4[i];
        int4 s = s4[i];
        int b0 = d.x >> 8, b1 = d.y >> 8, b2 = d.z >> 8, b3 = d.w >> 8;
        int r0 = atomicAdd(&hist[b0], 1);
        packed[base[b0] + r0] = ((unsigned)s.x << 8) | (unsigned)(d.x & 255);
        int r1 = atomicAdd(&hist[b1], 1);
        packed[base[b1] + r1] = ((unsigned)s.y << 8) | (unsigned)(d.y & 255);
        int r2 = atomicAdd(&hist[b2], 1);
        packed[base[b2] + r2] = ((unsigned)s.z << 8) | (unsigned)(d.z & 255);
        int r3 = atomicAdd(&hist[b3], 1);
        packed[base[b3] + r3] = ((unsigned)s.w << 8) | (unsigned)(d.w & 255);
    }
    for (int i = (lim4 << 2) + t; i < lim; i += BLK) {
        int d = dst[chunk0 + i];
        int b = d >> 8;
        int r = atomicAdd(&hist[b], 1);
        packed[base[b] + r] = ((unsigned)src[chunk0 + i] << 8) | (unsigned)(d & 255);
    }
}

// ---- stage 2: 4-way quarter-split per-bucket counting sort -----------------
// block = (bucket b, quarter qr). All 4 blocks of a bucket redundantly build
// the 256-counter histogram + scan (cheap LDS work); each scatters only the
// edges whose dstLocal is in its 64-node quarter (contiguous sub-window).
__global__ __launch_bounds__(BLK) void k_sort(const unsigned* __restrict__ packed,
                                              const int* __restrict__ bcnt,
                                              int* __restrict__ ssrc,
                                              int* __restrict__ rowbeg,
                                              int* __restrict__ rowcnt,
                                              float* __restrict__ dinv, int n) {
    __shared__ unsigned sp[STRIDE];   // 20 KB bucket staging
    __shared__ int cnt[NPB];
    __shared__ int offs[NPB];
    int bid = blockIdx.x;
    int b = bid >> 2;
    int qr = bid & 3;                  // quarter: local nodes qr*64 .. qr*64+63
    int t = threadIdx.x;
    int regionBase = b * STRIDE;
    int ecnt = bcnt[b * CPAD];
    cnt[t] = 0;
    __syncthreads();
    for (int i = t; i < ecnt; i += BLK) {
        unsigned p = packed[regionBase + i];
        sp[i] = p;
        atomicAdd(&cnt[p & 255u], 1);
    }
    __syncthreads();
    int v = cnt[t];
    offs[t] = v;
    __syncthreads();
    for (int off = 1; off < NPB; off <<= 1) {
        int x = (t >= off) ? offs[t - off] : 0;
        __syncthreads();
        offs[t] += x;
        __syncthreads();
    }
    int myoff = offs[t] - v;  // exclusive
    int node = (b << 8) + t;
    if ((t >> 6) == qr && node < n) {
        rowbeg[node] = regionBase + myoff;
        rowcnt[node] = v;
        dinv[node] = rsqrtf((float)(v + 1));   // +1 self-loop
    }
    __syncthreads();
    cnt[t] = regionBase + myoff;  // reuse as cursor
    __syncthreads();
    int lo = qr << 6, hi = lo + 64;
    for (int i = t; i < ecnt; i += BLK) {
        unsigned p = sp[i];
        int dl = (int)(p & 255u);
        if (dl >= lo && dl < hi) {
            int pos = atomicAdd(&cnt[dl], 1);
            ssrc[pos] = (int)(p >> 8);
        }
    }
}

// ---- layer kernels ---------------------------------------------------------

// hhat[n][c] = bf16( dinv[n] * sum_k x[n][k]*W1[k][c] )
// thread = 4 nodes x 16 channels; GRID-STRIDE persistent blocks: W loaded to
// LDS once per block, then loop over 256-node tiles (fixes 1.5 waves/CU).
__global__ __launch_bounds__(BLK) void k_gemm1(const float* __restrict__ x,
                                               const float* __restrict__ W1,
                                               const float* __restrict__ dinv,
                                               unsigned short* __restrict__ hhat,
                                               int n, int ntiles) {
    __shared__ float W[64 * 64];
    int t = threadIdx.x;
    #pragma unroll
    for (int i = 0; i < 16; ++i) W[t + BLK * i] = W1[t + BLK * i];
    __syncthreads();
    const int cg = t & 3;
    const int ng = t >> 2;
    const float* Wc = W + cg * 16;

    for (int tile = blockIdx.x; tile < ntiles; tile += gridDim.x) {
        const int node0 = tile * 256 + ng * 4;
        int nd[4];
        #pragma unroll
        for (int i = 0; i < 4; ++i) {
            int v = node0 + i;
            nd[i] = (v < n) ? v : (n - 1);
        }
        float4 acc[4][4];
        #pragma unroll
        for (int i = 0; i < 4; ++i)
            #pragma unroll
            for (int c = 0; c < 4; ++c) acc[i][c] = make_float4(0.f, 0.f, 0.f, 0.f);

        for (int k4 = 0; k4 < 16; ++k4) {
            float4 xv[4];
            #pragma unroll
            for (int i = 0; i < 4; ++i)
                xv[i] = ((const float4*)(x + (size_t)nd[i] * 64))[k4];
            #pragma unroll
            for (int kk = 0; kk < 4; ++kk) {
                const float4* wr = (const float4*)(Wc + (k4 * 4 + kk) * 64);
                float4 w0 = wr[0], w1 = wr[1], w2 = wr[2], w3 = wr[3];
                #pragma unroll
                for (int i = 0; i < 4; ++i) {
                    float xa[4] = {xv[i].x, xv[i].y, xv[i].z, xv[i].w};
                    float xs = xa[kk];
                    acc[i][0].x = fmaf(xs, w0.x, acc[i][0].x);
                    acc[i][0].y = fmaf(xs, w0.y, acc[i][0].y);
                    acc[i][0].z = fmaf(xs, w0.z, acc[i][0].z);
                    acc[i][0].w = fmaf(xs, w0.w, acc[i][0].w);
                    acc[i][1].x = fmaf(xs, w1.x, acc[i][1].x);
                    acc[i][1].y = fmaf(xs, w1.y, acc[i][1].y);
                    acc[i][1].z = fmaf(xs, w1.z, acc[i][1].z);
                    acc[i][1].w = fmaf(xs, w1.w, acc[i][1].w);
                    acc[i][2].x = fmaf(xs, w2.x, acc[i][2].x);
                    acc[i][2].y = fmaf(xs, w2.y, acc[i][2].y);
                    acc[i][2].z = fmaf(xs, w2.z, acc[i][2].z);
                    acc[i][2].w = fmaf(xs, w2.w, acc[i][2].w);
                    acc[i][3].x = fmaf(xs, w3.x, acc[i][3].x);
                    acc[i][3].y = fmaf(xs, w3.y, acc[i][3].y);
                    acc[i][3].z = fmaf(xs, w3.z, acc[i][3].z);
                    acc[i][3].w = fmaf(xs, w3.w, acc[i][3].w);
                }
            }
        }
        #pragma unroll
        for (int i = 0; i < 4; ++i) {
            int v = node0 + i;
            if (v < n) {
                float d = dinv[v];
                unsigned u0 = pack2bf(acc[i][0].x * d, acc[i][0].y * d);
                unsigned u1 = pack2bf(acc[i][0].z * d, acc[i][0].w * d);
                unsigned u2 = pack2bf(acc[i][1].x * d, acc[i][1].y * d);
                unsigned u3 = pack2bf(acc[i][1].z * d, acc[i][1].w * d);
                unsigned u4 = pack2bf(acc[i][2].x * d, acc[i][2].y * d);
                unsigned u5 = pack2bf(acc[i][2].z * d, acc[i][2].w * d);
                unsigned u6 = pack2bf(acc[i][3].x * d, acc[i][3].y * d);
                unsigned u7 = pack2bf(acc[i][3].z * d, acc[i][3].w * d);
                uint4* dst = (uint4*)(hhat + (size_t)v * 64 + cg * 16);
                dst[0] = make_uint4(u0, u1, u2, u3);
                dst[1] = make_uint4(u4, u5, u6, u7);
            }
        }
    }
}

// DUAL-node wave: nodes 2w and 2w+1, lane = channel (64). Interleaved 8-edge
// batches (up to 16 gathers in flight). All metadata/index loads wave-uniform.
// Fused layer-2 GEMV epilogue per node. (round-10/13 verified champion)
__global__ __launch_bounds__(BLK) void k_agg1(const unsigned short* __restrict__ hhat,
                                              const int* __restrict__ rowbeg,
                                              const int* __restrict__ rowcnt,
                                              const int* __restrict__ ssrc,
                                              const float* __restrict__ dinv,
                                              const float* __restrict__ b1,
                                              const float* __restrict__ W2,
                                              unsigned short* __restrict__ h2hat, int n) {
    int pair = __builtin_amdgcn_readfirstlane(
        (int)((blockIdx.x * BLK + threadIdx.x) >> 6));
    int lane = threadIdx.x & 63;
    int wid0 = pair << 1;
    if (wid0 >= n) return;
    int wid1 = wid0 + 1;
    bool has1 = (wid1 < n);
    const int g = lane >> 4;   // c-group for the fused GEMV
    const int j = lane & 15;   // output channel for the fused GEMV
    float w2r[16];
    #pragma unroll
    for (int k = 0; k < 16; ++k) w2r[k] = W2[(g * 16 + k) * 16 + j];

    int beg0 = rowbeg[wid0], cnt0 = rowcnt[wid0];
    int beg1 = 0, cnt1 = 0;
    if (has1) { beg1 = rowbeg[wid1]; cnt1 = rowcnt[wid1]; }
    float a0 = bf2f(hhat[((size_t)wid0 << 6) + lane]);  // self-loop
    float a1 = 0.f;
    if (has1) a1 = bf2f(hhat[((size_t)wid1 << 6) + lane]);
    int e0 = 0, e1 = 0;
    // interleaved main: 16 gathers in flight
    while (e0 + 8 <= cnt0 && e1 + 8 <= cnt1) {
        float r0 = gather8(hhat, ssrc, beg0 + e0, lane);
        float r1 = gather8(hhat, ssrc, beg1 + e1, lane);
        a0 += r0;
        a1 += r1;
        e0 += 8; e1 += 8;
    }
    for (; e0 + 8 <= cnt0; e0 += 8) a0 += gather8(hhat, ssrc, beg0 + e0, lane);
    for (; e1 + 8 <= cnt1; e1 += 8) a1 += gather8(hhat, ssrc, beg1 + e1, lane);
    if (e0 + 4 <= cnt0) { a0 += gather4(hhat, ssrc, beg0 + e0, lane); e0 += 4; }
    if (e1 + 4 <= cnt1) { a1 += gather4(hhat, ssrc, beg1 + e1, lane); e1 += 4; }
    for (; e0 < cnt0; ++e0) a0 += bf2f(hhat[((size_t)ssrc[beg0 + e0] << 6) + lane]);
    for (; e1 < cnt1; ++e1) a1 += bf2f(hhat[((size_t)ssrc[beg1 + e1] << 6) + lane]);

    // fused GEMV epilogue, node 0
    {
        float dv = dinv[wid0];
        float h = fmaxf(fmaf(dv, a0, b1[lane]), 0.f);
        float part = 0.f;
        #pragma unroll
        for (int k = 0; k < 16; ++k)
            part = fmaf(__shfl(h, g * 16 + k, 64), w2r[k], part);
        part += __shfl_xor(part, 16, 64);
        part += __shfl_xor(part, 32, 64);
        if (g == 0) h2hat[(size_t)wid0 * 16 + j] = f2bf(part * dv);
    }
    if (has1) {
        float dv = dinv[wid1];
        float h = fmaxf(fmaf(dv, a1, b1[lane]), 0.f);
        float part = 0.f;
        #pragma unroll
        for (int k = 0; k < 16; ++k)
            part = fmaf(__shfl(h, g * 16 + k, 64), w2r[k], part);
        part += __shfl_xor(part, 16, 64);
        part += __shfl_xor(part, 32, 64);
        if (g == 0) h2hat[(size_t)wid1 * 16 + j] = f2bf(part * dv);
    }
}

// DUAL-node wave layer 2: nodes 2w, 2w+1; 64 lanes = 4 edge-slots x 16 ch;
// uniform ssrc loads + cndmask select by slot; interleaved 8-edge batches.
__global__ __launch_bounds__(BLK) void k_agg2(const unsigned short* __restrict__ h2,
                                              const int* __restrict__ rowbeg,
                                              const int* __restrict__ rowcnt,
                                              const int* __restrict__ ssrc,
                                              const float* __restrict__ dinv,
                                              const float* __restrict__ b2,
                                              float* __restrict__ out, int n) {
    int pair = __builtin_amdgcn_readfirstlane(
        (int)((blockIdx.x * BLK + threadIdx.x) >> 6));
    int lane = threadIdx.x & 63;
    int w0 = pair << 1;
    if (w0 >= n) return;
    int w1 = w0 + 1;
    bool has1 = (w1 < n);
    int q = lane >> 4;      // edge slot 0..3
    int c = lane & 15;      // channel
    int beg0 = rowbeg[w0], cnt0 = rowcnt[w0];
    int beg1 = 0, cnt1 = 0;
    if (has1) { beg1 = rowbeg[w1]; cnt1 = rowcnt[w1]; }
    float a0 = 0.f, a1 = 0.f;
    int e0 = 0, e1 = 0;
    while (e0 + 8 <= cnt0 && e1 + 8 <= cnt1) {
        int p0 = beg0 + e0, p1 = beg1 + e1;
        int x0 = ssrc[p0 + 0], x1 = ssrc[p0 + 1], x2 = ssrc[p0 + 2], x3 = ssrc[p0 + 3];
        int x4 = ssrc[p0 + 4], x5 = ssrc[p0 + 5], x6 = ssrc[p0 + 6], x7 = ssrc[p0 + 7];
        int y0 = ssrc[p1 + 0], y1 = ssrc[p1 + 1], y2 = ssrc[p1 + 2], y3 = ssrc[p1 + 3];
        int y4 = ssrc[p1 + 4], y5 = ssrc[p1 + 5], y6 = ssrc[p1 + 6], y7 = ssrc[p1 + 7];
        int sA0 = sel4(x0, x1, x2, x3, q), sB0 = sel4(x4, x5, x6, x7, q);
        int sA1 = sel4(y0, y1, y2, y3, q), sB1 = sel4(y4, y5, y6, y7, q);
        float vA0 = bf2f(h2[((size_t)sA0 << 4) + c]);
        float vB0 = bf2f(h2[((size_t)sB0 << 4) + c]);
        float vA1 = bf2f(h2[((size_t)sA1 << 4) + c]);
        float vB1 = bf2f(h2[((size_t)sB1 << 4) + c]);
        a0 += vA0 + vB0;
        a1 += vA1 + vB1;
        e0 += 8; e1 += 8;
    }
    // drain node 0
    for (; e0 + 8 <= cnt0; e0 += 8) {
        int p0 = beg0 + e0;
        int x0 = ssrc[p0 + 0], x1 = ssrc[p0 + 1], x2 = ssrc[p0 + 2], x3 = ssrc[p0 + 3];
        int x4 = ssrc[p0 + 4], x5 = ssrc[p0 + 5], x6 = ssrc[p0 + 6], x7 = ssrc[p0 + 7];
        int sA = sel4(x0, x1, x2, x3, q), sB = sel4(x4, x5, x6, x7, q);
        a0 += bf2f(h2[((size_t)sA << 4) + c]) + bf2f(h2[((size_t)sB << 4) + c]);
    }
    if (e0 + 4 <= cnt0) {
        int p0 = beg0 + e0;
        int x0 = ssrc[p0 + 0], x1 = ssrc[p0 + 1], x2 = ssrc[p0 + 2], x3 = ssrc[p0 + 3];
        a0 += bf2f(h2[((size_t)sel4(x0, x1, x2, x3, q) << 4) + c]);
        e0 += 4;
    }
    if (e0 + q < cnt0)
        a0 += bf2f(h2[((size_t)ssrc[beg0 + e0 + q] << 4) + c]);
    // drain node 1
    for (; e1 + 8 <= cnt1; e1 += 8) {
        int p1 = beg1 + e1;
        int y0 = ssrc[p1 + 0], y1 = ssrc[p1 + 1], y2 = ssrc[p1 + 2], y3 = ssrc[p1 + 3];
        int y4 = ssrc[p1 + 4], y5 = ssrc[p1 + 5], y6 = ssrc[p1 + 6], y7 = ssrc[p1 + 7];
        int sA = sel4(y0, y1, y2, y3, q), sB = sel4(y4, y5, y6, y7, q);
        a1 += bf2f(h2[((size_t)sA << 4) + c]) + bf2f(h2[((size_t)sB << 4) + c]);
    }
    if (has1 && e1 + 4 <= cnt1) {
        int p1 = beg1 + e1;
        int y0 = ssrc[p1 + 0], y1 = ssrc[p1 + 1], y2 = ssrc[p1 + 2], y3 = ssrc[p1 + 3];
        a1 += bf2f(h2[((size_t)sel4(y0, y1, y2, y3, q) << 4) + c]);
        e1 += 4;
    }
    if (has1 && e1 + q < cnt1)
        a1 += bf2f(h2[((size_t)ssrc[beg1 + e1 + q] << 4) + c]);

    a0 += __shfl_xor(a0, 16, 64);
    a0 += __shfl_xor(a0, 32, 64);
    a1 += __shfl_xor(a1, 16, 64);
    a1 += __shfl_xor(a1, 32, 64);
    if (q == 0) {
        float self0 = bf2f(h2[((size_t)w0 << 4) + c]);
        out[((size_t)w0 << 4) + c] = fmaf(dinv[w0], a0 + self0, b2[c]);
        if (has1) {
            float self1 = bf2f(h2[((size_t)w1 << 4) + c]);
            out[((size_t)w1 << 4) + c] = fmaf(dinv[w1], a1 + self1, b2[c]);
        }
    }
}

} // namespace

extern "C" void kernel_launch(void* const* d_in, const int* in_sizes, int n_in,
                              void* d_out, int out_size, void* d_ws, size_t ws_size,
                              hipStream_t stream) {
    const float* x  = (const float*)d_in[0];
    const int*   ei = (const int*)d_in[1];
    const float* W1 = (const float*)d_in[2];
    const float* b1 = (const float*)d_in[3];
    const float* W2 = (const float*)d_in[4];
    const float* b2 = (const float*)d_in[5];
    float* out = (float*)d_out;

    const int N = in_sizes[0] / 64;
    const int E = in_sizes[1] / 2;
    const int* src = ei;
    const int* dst = ei + E;
    const int nb = (N + NPB - 1) / NPB;   // buckets (<=1024)

    char* ws = (char*)d_ws;
    size_t off = 0;
    auto alloc = [&](size_t bytes) -> char* {
        char* p = ws + off;
        off = (off + bytes + 255) & ~(size_t)255;
        return p;
    };
    int*            bcnt   = (int*)alloc((size_t)1024 * CPAD * 4);
    int*            rowbeg = (int*)alloc((size_t)N * 4);
    int*            rowcnt = (int*)alloc((size_t)N * 4);
    float*          dinv   = (float*)alloc((size_t)N * 4);
    unsigned*       packed = (unsigned*)alloc((size_t)nb * STRIDE * 4);
    int*            ssrc   = (int*)alloc((size_t)nb * STRIDE * 4);
    unsigned short* hhat   = (unsigned short*)alloc((size_t)N * 64 * 2);
    unsigned short* h2hat  = (unsigned short*)alloc((size_t)N * 16 * 2);

    const int ntiles = (N + 255) / 256;
    const int g1grid = (ntiles < 1024) ? ntiles : 1024;
    const int nchunks = (E + PCHUNK - 1) / PCHUNK;
    const int npairs = (N + 1) / 2;
    const int nb_p = (int)(((long long)npairs * 64 + BLK - 1) / BLK);  // dual-node

    const int zn = nb * CPAD;
    k_zero<<<(zn + BLK - 1) / BLK, BLK, 0, stream>>>(bcnt, zn);
    k_part<<<nchunks, BLK, 0, stream>>>(src, dst, bcnt, packed, E, nb);
    k_sort<<<nb * 4, BLK, 0, stream>>>(packed, bcnt, ssrc, rowbeg, rowcnt, dinv, N);

    k_gemm1<<<g1grid, BLK, 0, stream>>>(x, W1, dinv, hhat, N, ntiles);
    k_agg1<<<nb_p, BLK, 0, stream>>>(hhat, rowbeg, rowcnt, ssrc, dinv, b1, W2,
                                     h2hat, N);
    k_agg2<<<nb_p, BLK, 0, stream>>>(h2hat, rowbeg, rowcnt, ssrc, dinv, b2, out, N);
}